// Round 4
// baseline (1303.347 us; speedup 1.0000x reference)
//
#include <hip/hip_runtime.h>
#include <cfloat>
#include <cstdint>

typedef unsigned short u16;

// Problem constants
#define NTOK   131072      // B*H*W
#define DIM    256
#define NCODE  1024
#define HW     4096
#define PLANE  1048576     // DIM*HW
#define DECAYF 0.9f
#define EPSF   1e-5f

// d_out float offsets (outputs concatenated in return order)
#define O_OUT     0
#define O_LOSS    33554432
#define O_IDX     33554433
#define O_NEWEMB  33685505
#define O_NCS     33947649
#define O_NEE     33948673

// scratch regions INSIDE O_OUT (float offsets) — k_quant overwrites O_OUT last
#define P_XS      0          // Xs bf16 [131072][256] = 16.7M floats-equiv
#define P_VF      19922944   // [131072] final approx v1
#define P_DW      20054016   // [8][262144] dw partials
#define P_BT      22151168   // Bt_sw swizzled tiles, 1 MB
#define P_ENORM64 22413312   // [1024] doubles (2048 floats), byte-offset %8 == 0

// ws float offsets (tiny, safe for any ws_size)
#define WS_ENORM  0
#define WS_CNT    1024
#define WS_LOSS   2048
#define WS_RC     2049
#define WS_LIST   2050       // [32768]
#define WS_SMOOTH 34818

#define REF_CAP 32768
#define DELTA   0.25f
#define RT      16           // refine tokens per block-batch

typedef __attribute__((ext_vector_type(8))) short bf16x8;
typedef __attribute__((ext_vector_type(4))) float f32x4;

__device__ __forceinline__ u16 bf16_rne(float f) {
    unsigned int u = __float_as_uint(f);
    unsigned int r = u + 0x7FFF + ((u >> 16) & 1);
    return (u16)(r >> 16);
}
__device__ __forceinline__ float bf16_to_f(u16 s) {
    return __uint_as_float(((unsigned int)s) << 16);
}
__device__ __forceinline__ void gload_lds16(const void* g, void* l) {
    __builtin_amdgcn_global_load_lds(
        (const __attribute__((address_space(1))) unsigned int*)g,
        (__attribute__((address_space(3))) unsigned int*)l, 16, 0, 0);
}

// ---------------------------------------------------------------- ||e_k||^2
__global__ void k_enorm(const float* __restrict__ embed, float* __restrict__ enorm,
                        double* __restrict__ enorm64) {
    int k = blockIdx.x * 256 + threadIdx.x;
    double s = 0.0;
    for (int d = 0; d < DIM; ++d) {
        float e = embed[(size_t)d * NCODE + k];
        s += (double)e * (double)e;
    }
    enorm[k] = (float)s;
    enorm64[k] = s;
}

// ------------------- k_xs: x [b][d][hw] fp32 -> Xs [n][256] bf16 (transpose) + sum(x^2)
__global__ __launch_bounds__(256) void k_xs(const float* __restrict__ x,
                                            u16* __restrict__ Xs,
                                            float* __restrict__ loss_acc)
{
    __shared__ float tile[64 * 65];
    __shared__ float red[256];
    const int tid = threadIdx.x;
    const int blk = blockIdx.x;          // 8192 = 32 b x 4 dc x 64 hwc
    const int b = blk >> 8;
    const int dc = (blk >> 6) & 3;
    const int hwc = blk & 63;
    const int d0 = dc * 64, hw0 = hwc * 64;
    const int r = tid >> 2, s = tid & 3;
    float sq = 0.f;
#pragma unroll
    for (int j = 0; j < 4; ++j) {
        float4 v = *(const float4*)&x[(size_t)b * PLANE + (size_t)(d0 + r) * HW + hw0 + s * 16 + j * 4];
        int c = s * 16 + j * 4;
        tile[r * 65 + c + 0] = v.x; tile[r * 65 + c + 1] = v.y;
        tile[r * 65 + c + 2] = v.z; tile[r * 65 + c + 3] = v.w;
        sq = fmaf(v.x, v.x, sq); sq = fmaf(v.y, v.y, sq);
        sq = fmaf(v.z, v.z, sq); sq = fmaf(v.w, v.w, sq);
    }
    __syncthreads();
    const int tk = tid >> 2, dq = tid & 3;
    u16 us[16];
#pragma unroll
    for (int j = 0; j < 16; ++j)
        us[j] = bf16_rne(tile[(dq * 16 + j) * 65 + tk]);
    size_t ob = (size_t)(b * 4096 + hw0 + tk) * 256 + d0 + dq * 16;
    *(uint4*)&Xs[ob]     = *(uint4*)&us[0];
    *(uint4*)&Xs[ob + 8] = *(uint4*)&us[8];
    red[tid] = sq; __syncthreads();
    for (int st = 128; st > 0; st >>= 1) {
        if (tid < st) red[tid] += red[tid + st];
        __syncthreads();
    }
    if (tid == 0) atomicAdd(loss_acc, red[0]);
}

// ------------------- k_bt: embed -> swizzled bf16 tiles Bt_sw[cc*16+kc][512 granules]
// kc 0..7 = E_hi rows (d = kc*32..), kc 8..15 = E_lo.
// Granule g of row n stored at slot (g + n + (n>>2)) & 3  (2-way-free bank swizzle).
__global__ __launch_bounds__(256) void k_bt(const float* __restrict__ embed, u16* __restrict__ Bt)
{
    const int tile = blockIdx.x;          // 128 tiles
    const int cc = tile >> 4, kc = tile & 15;
    const int seg = kc >> 3, dbase = (kc & 7) * 32;
    const int tid = threadIdx.x;
#pragma unroll
    for (int g2 = 0; g2 < 2; ++g2) {
        int p = g2 * 256 + tid;
        int n = p >> 2, s = p & 3, lg = (s - n - (n >> 2)) & 3;
        int code = cc * 128 + n;
        u16 us[8];
#pragma unroll
        for (int e = 0; e < 8; ++e) {
            int d = dbase + lg * 8 + e;
            float E = embed[(size_t)d * NCODE + code];
            u16 hi = bf16_rne(E);
            us[e] = seg ? bf16_rne(E - bf16_to_f(hi)) : hi;
        }
        *(uint4*)&Bt[(size_t)tile * 4096 + (size_t)p * 8] = *(uint4*)&us[0];
    }
}

// ------------------- k_dist v3: persistent-A MFMA GEMM, all 1024 codes per block
// grid 1024: block = 128 tokens x 1024 codes (cc loop in-block, A staged once).
// B staged via 3-deep LDS ring, 2-ahead prefetch, counted vmcnt.
// SYNC ORDER (v2 bugfix): vmcnt(N) BEFORE s_barrier — vmcnt is per-wave and each
// wave stages only 1/4 of each buffer; the wait must be certified before the
// barrier publishes it block-wide. (v2 had barrier-then-wait: cross-wave race.)
__global__ __launch_bounds__(256) void k_dist(
    const u16* __restrict__ Xs, const u16* __restrict__ Bt,
    const float* __restrict__ enorm,
    float* __restrict__ out_idx, float* __restrict__ vfo, float* __restrict__ loss_acc,
    int* __restrict__ refcnt, int* __restrict__ reflist)
{
    // LDS (u16 units): A [0,32768) = 64KB (8 slices of 4096 per kc8)
    //                  ring r at 32768 + r*8192 (3 x 16KB)
    //                  epi floats at u16 57344 (768 floats)
    //                  enorm floats at u16 58880 (1024 floats)
    __shared__ __align__(16) u16 lds[60928];
    const int tid = threadIdx.x;
    const int w = tid >> 6, l = tid & 63;
    const int n0 = blockIdx.x * 128;
    const int mh = w & 1, nh = w >> 1;
    const int lane15 = l & 15, quad = l >> 4;

    // ---------- prologue: issue A (16 rounds), enorm (1 round), B step0, B step1
#pragma unroll
    for (int rr = 0; rr < 16; ++rr) {
        int p = rr * 256 + tid;
        int kc8p = p >> 9;
        int q = p & 511;
        int m = q >> 2, s = q & 3;
        int lg = (s - m - (m >> 2)) & 3;
        gload_lds16(Xs + (size_t)(n0 + m) * 256 + kc8p * 32 + lg * 8,
                    &lds[(size_t)(rr * 256 + w * 64) * 8]);
    }
    gload_lds16((const char*)enorm + (size_t)tid * 16,
                &lds[58880 + (size_t)(w * 64) * 8]);

#define STAGE_B(cc_, kc8_, ring_) do {                                               \
    _Pragma("unroll")                                                                \
    for (int rr_ = 0; rr_ < 4; ++rr_) {                                              \
        int p_ = rr_ * 256 + tid;                                                    \
        int seg_ = p_ >> 9;                                                          \
        gload_lds16(Bt + (size_t)((cc_) * 16 + seg_ * 8 + (kc8_)) * 4096             \
                       + (size_t)(p_ & 511) * 8,                                     \
                    &lds[32768 + (ring_) * 8192 + (size_t)(rr_ * 256 + w * 64) * 8]); \
    } } while (0)

    STAGE_B(0, 0, 0);
    STAGE_B(0, 1, 1);

    float rv1 = FLT_MAX, rv2 = FLT_MAX; int rk1 = 1 << 30;
    float* epi = (float*)&lds[57344];
    const float* enf = (const float*)&lds[58880];

    for (int cc = 0; cc < 8; ++cc) {
        f32x4 acc[4][4];
#pragma unroll
        for (int i = 0; i < 4; ++i)
#pragma unroll
            for (int j = 0; j < 4; ++j) acc[i][j] = (f32x4)0.f;

#pragma unroll
        for (int kc8 = 0; kc8 < 8; ++kc8) {
            const int i = cc * 8 + kc8;
            // wait own loads-for-step-i (issued 2 steps ago) BEFORE the barrier,
            // so the barrier certifies all waves' staging of this step complete.
            if (cc == 7 && kc8 == 7) asm volatile("s_waitcnt vmcnt(0)" ::: "memory");
            else                     asm volatile("s_waitcnt vmcnt(4)" ::: "memory");
            __builtin_amdgcn_s_barrier();

            if (i + 2 < 64) {                  // prefetch step i+2 into ring (i+2)%3
                const int i2 = i + 2;
                STAGE_B(i2 >> 3, i2 & 7, i2 % 3);
            }

            const u16* bufB = &lds[32768 + (i % 3) * 8192];
            bf16x8 af[4];
#pragma unroll
            for (int mt = 0; mt < 4; ++mt) {
                int m = mh * 64 + mt * 16 + lane15;
                int slot = (quad + m + (m >> 2)) & 3;
                af[mt] = *(const bf16x8*)&lds[(size_t)kc8 * 4096 + (size_t)(m * 4 + slot) * 8];
            }
#pragma unroll
            for (int seg = 0; seg < 2; ++seg)
#pragma unroll
                for (int nt = 0; nt < 4; ++nt) {
                    int n = nh * 64 + nt * 16 + lane15;
                    int slot = (quad + n + (n >> 2)) & 3;
                    bf16x8 bfr = *(const bf16x8*)&bufB[(size_t)(seg * 512 + n * 4 + slot) * 8];
#pragma unroll
                    for (int mt = 0; mt < 4; ++mt)
                        acc[mt][nt] = __builtin_amdgcn_mfma_f32_16x16x32_bf16(af[mt], bfr, acc[mt][nt], 0, 0, 0);
                }
        }

        // ---- epilogue for this cc: dist = ||e||^2 - 2 dot ; top-2 over 128 codes
        float ev[4]; int ec[4];
#pragma unroll
        for (int nt = 0; nt < 4; ++nt) {
            ec[nt] = cc * 128 + nh * 64 + nt * 16 + lane15;
            ev[nt] = enf[ec[nt]];
        }
        float r1[4][4], r2[4][4]; int rk[4][4];
#pragma unroll
        for (int mt = 0; mt < 4; ++mt)
#pragma unroll
            for (int rg = 0; rg < 4; ++rg) {
                float v1 = FLT_MAX, v2 = FLT_MAX; int k1 = 1 << 30;
#pragma unroll
                for (int nt = 0; nt < 4; ++nt) {
                    float d = fmaf(-2.f, acc[mt][nt][rg], ev[nt]);
                    if (d < v1) { v2 = v1; v1 = d; k1 = ec[nt]; }
                    else v2 = fminf(v2, d);
                }
                r1[mt][rg] = v1; r2[mt][rg] = v2; rk[mt][rg] = k1;
            }
#pragma unroll
        for (int mask = 1; mask <= 8; mask <<= 1) {
#pragma unroll
            for (int mt = 0; mt < 4; ++mt)
#pragma unroll
                for (int rg = 0; rg < 4; ++rg) {
                    float ov1 = __shfl_xor(r1[mt][rg], mask);
                    float ov2 = __shfl_xor(r2[mt][rg], mask);
                    int   ok  = __shfl_xor(rk[mt][rg], mask);
                    if (ov1 < r1[mt][rg] || (ov1 == r1[mt][rg] && ok < rk[mt][rg])) {
                        r2[mt][rg] = fminf(r1[mt][rg], ov2);
                        r1[mt][rg] = ov1; rk[mt][rg] = ok;
                    } else {
                        r2[mt][rg] = fminf(r2[mt][rg], ov1);
                    }
                }
        }
        if (lane15 == 0) {
#pragma unroll
            for (int mt = 0; mt < 4; ++mt)
#pragma unroll
                for (int rg = 0; rg < 4; ++rg) {
                    int t = mh * 64 + mt * 16 + quad * 4 + rg;
                    float* p = &epi[(nh * 128 + t) * 3];
                    p[0] = r1[mt][rg]; p[1] = r2[mt][rg]; p[2] = __int_as_float(rk[mt][rg]);
                }
        }
        asm volatile("s_waitcnt lgkmcnt(0)" ::: "memory");
        __builtin_amdgcn_s_barrier();
        if (tid < 128) {
            const float* p0 = &epi[tid * 3];
            const float* p1 = &epi[(128 + tid) * 3];
            float v1 = p0[0], v2 = p0[1]; int k1 = __float_as_int(p0[2]);
            float a1 = p1[0], a2 = p1[1]; int ak = __float_as_int(p1[2]);
            if (a1 < v1 || (a1 == v1 && ak < k1)) { v2 = fminf(v1, a2); v1 = a1; k1 = ak; }
            else v2 = fminf(v2, a1);
            if (v1 < rv1 || (v1 == rv1 && k1 < rk1)) { rv2 = fminf(rv1, v2); rv1 = v1; rk1 = k1; }
            else rv2 = fminf(rv2, v1);
        }
        // epi not reused until next cc's epilogue (>=8 barriers away) — no extra barrier
    }

    // ---- final outputs (old k_amin folded in)
    if (tid < 128) {
        int n = n0 + tid;
        out_idx[n] = (float)rk1;
        vfo[n] = rv1;
        if (rv2 - rv1 < DELTA) {
            int pos = atomicAdd(refcnt, 1);
            if (pos < REF_CAP) reflist[pos] = n;
        }
    }
    __syncthreads();
    float* red = epi;
    red[tid] = (tid < 128) ? rv1 : 0.f;
    __syncthreads();
    for (int s = 128; s > 0; s >>= 1) {
        if (tid < s) red[tid] += red[tid + s];
        __syncthreads();
    }
    if (tid == 0) atomicAdd(loss_acc, red[0]);
#undef STAGE_B
}

// ------------------- k_refine v2: batched exact fp64 argmin for flagged tokens
// RT tokens share one pass over embed: dist_k = enorm64[k] + sum_d e[d,k]*(-2 x[d]).
__global__ __launch_bounds__(256) void k_refine(
    const float* __restrict__ x, const float* __restrict__ embed,
    const double* __restrict__ enorm64,
    float* __restrict__ out_idx, const int* __restrict__ refcnt,
    const int* __restrict__ reflist, const float* __restrict__ vf,
    float* __restrict__ loss_acc)
{
    __shared__ double xm2[RT][DIM];     // -2*x per token (32 KB)
    __shared__ int toks[RT];
    __shared__ double wv[4][RT];
    __shared__ int wk[4][RT];
    const int tid = threadIdx.x;
    const int w = tid >> 6, l = tid & 63;
    const int cnt = min(*refcnt, REF_CAP);
    for (int base = blockIdx.x * RT; base < cnt; base += gridDim.x * RT) {
        const int nb = min(RT, cnt - base);
        for (int j = 0; j < nb; ++j) {
            int n = reflist[base + j];
            if (tid == 0) toks[j] = n;
            int b = n >> 12, hw = n & 4095;
            float xv = x[(size_t)b * PLANE + (size_t)tid * HW + hw];
            xm2[j][tid] = -2.0 * (double)xv;
        }
        __syncthreads();

        double bv[RT]; int bk[RT];
#pragma unroll
        for (int j = 0; j < RT; ++j) { bv[j] = 1e300; bk[j] = 0; }
#pragma unroll 1
        for (int c = 0; c < 4; ++c) {
            const int k = c * 256 + tid;
            double acc[RT];
#pragma unroll
            for (int j = 0; j < RT; ++j) acc[j] = 0.0;
            const float* ep = embed + k;
#pragma unroll 4
            for (int d = 0; d < DIM; ++d) {
                double ed = (double)ep[(size_t)d * NCODE];
#pragma unroll
                for (int j = 0; j < RT; ++j)
                    acc[j] = fma(ed, xm2[j][d], acc[j]);
            }
            double e2 = enorm64[k];
#pragma unroll
            for (int j = 0; j < RT; ++j) {
                double dist = e2 + acc[j];
                if (dist < bv[j]) { bv[j] = dist; bk[j] = k; }
            }
        }

#pragma unroll
        for (int j = 0; j < RT; ++j) {
            double v = bv[j]; int kk = bk[j];
#pragma unroll
            for (int m = 1; m < 64; m <<= 1) {
                double ov = __shfl_xor(v, m);
                int ok = __shfl_xor(kk, m);
                if (ov < v || (ov == v && ok < kk)) { v = ov; kk = ok; }
            }
            if (l == 0) { wv[w][j] = v; wk[w][j] = kk; }
        }
        __syncthreads();
        if (tid < nb) {
            double v = wv[0][tid]; int kk = wk[0][tid];
#pragma unroll
            for (int wi = 1; wi < 4; ++wi) {
                double ov = wv[wi][tid]; int ok = wk[wi][tid];
                if (ov < v || (ov == v && ok < kk)) { v = ov; kk = ok; }
            }
            int n = toks[tid];
            out_idx[n] = (float)kk;
            atomicAdd(loss_acc, (float)(v - (double)vf[n]));
        }
        __syncthreads();
    }
}

// ------------------- k_cnt: ref_count (post-refine)
__global__ __launch_bounds__(256) void k_cnt(const float* __restrict__ out_idx, float* __restrict__ cnt) {
    const int n = blockIdx.x * 256 + threadIdx.x;
    atomicAdd(&cnt[(int)out_idx[n]], 1.0f);
}

// ------------------- k_dw: dw segment-sum via LDS tiles (nc=8 fixed)
__global__ __launch_bounds__(256) void k_dw(
    const float* __restrict__ x, const float* __restrict__ out_idx, float* __restrict__ part)
{
    __shared__ float tile[NCODE * 9];
    const int tid = threadIdx.x;
    const int slice = blockIdx.x & 31;
    const int chunk = blockIdx.x >> 5;
    const int d0 = slice * 8;
    for (int i = tid; i < NCODE * 9; i += 256) tile[i] = 0.f;
    __syncthreads();
    const int nbeg = chunk * (NTOK / 8);
    for (int t = tid; t < NTOK / 8; t += 256) {
        const int n = nbeg + t;
        const int b = n >> 12, hw = n & 4095;
        const int k = (int)out_idx[n];
        const float* xb = x + (size_t)b * PLANE + hw;
        float* tp = tile + k * 9;
#pragma unroll
        for (int dl = 0; dl < 8; ++dl)
            unsafeAtomicAdd(&tp[dl], xb[(size_t)(d0 + dl) * HW]);
    }
    __syncthreads();
    for (int i = tid; i < 8 * NCODE; i += 256) {
        const int dl = i >> 10, k = i & (NCODE - 1);
        part[((size_t)chunk * DIM + d0 + dl) * NCODE + k] = tile[k * 9 + dl];
    }
}

// ------------------- k_fin_cs: new_cluster_size + smoothing
__global__ __launch_bounds__(1024) void k_fin_cs(
    const float* __restrict__ cs_in, const float* __restrict__ cnt,
    float* __restrict__ out_ncs, float* __restrict__ smooth)
{
    const int k = threadIdx.x;
    float ncs = cs_in[k] * DECAYF + (1.f - DECAYF) * cnt[k];
    out_ncs[k] = ncs;
    __shared__ float red[1024];
    red[k] = ncs; __syncthreads();
    for (int s = 512; s > 0; s >>= 1) {
        if (k < s) red[k] += red[k + s];
        __syncthreads();
    }
    float n = red[0];
    smooth[k] = n * ((ncs + EPSF) / (n + ncs * EPSF));
}

// ------------------- k_fin_emb: sum dw partials, new_ema_embed, new_embed
__global__ __launch_bounds__(256) void k_fin_emb(
    const float* __restrict__ ema, const float* __restrict__ part,
    const float* __restrict__ smooth, float* __restrict__ out_ne, float* __restrict__ out_nee)
{
    const int i = blockIdx.x * 256 + threadIdx.x;
    const int k = i & (NCODE - 1);
    float dw = 0.f;
    for (int c = 0; c < 8; ++c) dw += part[(size_t)c * (DIM * NCODE) + i];
    float nee = ema[i] * DECAYF + (1.f - DECAYF) * dw;
    out_nee[i] = nee;
    out_ne[i] = nee / smooth[k];
}

// ------------------- k_quant: pure gather write (runs LAST, overwrites scratch)
__global__ __launch_bounds__(256) void k_quant(
    const float* __restrict__ embed, const float* __restrict__ out_idx, float* __restrict__ out_q)
{
    const int n = blockIdx.x * 256 + threadIdx.x;
    const int b = n >> 12, hw = n & 4095;
    const int idx = (int)out_idx[n];
    const size_t base = (size_t)b * PLANE + hw;
    for (int d = 0; d < DIM; ++d)
        out_q[base + (size_t)d * HW] = embed[(size_t)d * NCODE + idx];
}

// ------------------- k_loss: finalize scalar
__global__ void k_loss(const float* __restrict__ loss_acc, float* __restrict__ out_loss) {
    out_loss[0] = 0.25f * loss_acc[0] / 33554432.f;
}

extern "C" void kernel_launch(void* const* d_in, const int* in_sizes, int n_in,
                              void* d_out, int out_size, void* d_ws, size_t ws_size,
                              hipStream_t stream) {
    const float* x     = (const float*)d_in[0];
    const float* embed = (const float*)d_in[1];
    const float* csz   = (const float*)d_in[2];
    const float* ema   = (const float*)d_in[3];
    float* out = (float*)d_out;
    float* ws  = (float*)d_ws;

    u16* Xs = (u16*)(out + P_XS);
    u16* Bt = (u16*)(out + P_BT);
    double* enorm64 = (double*)(out + P_ENORM64);

    hipMemsetAsync(ws + WS_CNT, 0, (size_t)(WS_RC + 1 - WS_CNT) * sizeof(float), stream);

    k_enorm<<<4, 256, 0, stream>>>(embed, ws + WS_ENORM, enorm64);
    k_xs<<<8192, 256, 0, stream>>>(x, Xs, ws + WS_LOSS);
    k_bt<<<128, 256, 0, stream>>>(embed, Bt);
    k_dist<<<1024, 256, 0, stream>>>(Xs, Bt, ws + WS_ENORM,
                                     out + O_IDX, out + P_VF, ws + WS_LOSS,
                                     (int*)(ws + WS_RC), (int*)(ws + WS_LIST));
    k_refine<<<1024, 256, 0, stream>>>(x, embed, enorm64, out + O_IDX,
                                       (const int*)(ws + WS_RC), (const int*)(ws + WS_LIST),
                                       out + P_VF, ws + WS_LOSS);
    k_cnt<<<NTOK / 256, 256, 0, stream>>>(out + O_IDX, ws + WS_CNT);
    k_dw<<<256, 256, 0, stream>>>(x, out + O_IDX, out + P_DW);
    k_fin_cs<<<1, 1024, 0, stream>>>(csz, ws + WS_CNT, out + O_NCS, ws + WS_SMOOTH);
    k_fin_emb<<<1024, 256, 0, stream>>>(ema, out + P_DW, ws + WS_SMOOTH,
                                        out + O_NEWEMB, out + O_NEE);
    k_quant<<<NTOK / 256, 256, 0, stream>>>(embed, out + O_IDX, out + O_OUT);
    k_loss<<<1, 1, 0, stream>>>(ws + WS_LOSS, out + O_LOSS);
}

// Round 5
// 1271.959 us; speedup vs baseline: 1.0247x; 1.0247x over previous
//
#include <hip/hip_runtime.h>
#include <cfloat>
#include <cstdint>

typedef unsigned short u16;

// Problem constants
#define NTOK   131072      // B*H*W
#define DIM    256
#define NCODE  1024
#define HW     4096
#define PLANE  1048576     // DIM*HW
#define DECAYF 0.9f
#define EPSF   1e-5f

// d_out float offsets (outputs concatenated in return order)
#define O_OUT     0
#define O_LOSS    33554432
#define O_IDX     33554433
#define O_NEWEMB  33685505
#define O_NCS     33947649
#define O_NEE     33948673

// scratch regions INSIDE O_OUT (float offsets) — k_quant overwrites O_OUT last
#define P_XS      0          // Xs bf16 [131072][256]
#define P_V1      16777216   // [8][131072]
#define P_V2      17825792
#define P_KK      18874368
#define P_VF      19922944   // [131072] final approx v1
#define P_DW      20054016   // [8][262144] dw partials
#define P_BT      22151168   // Bt_sw swizzled tiles, 1 MB
#define P_ENORM64 22413312   // [1024] doubles (2048 floats), byte-offset %8 == 0
#define P_HLIST   22415360   // [32768] ints: hard-token list (fp32 gap <= MARGIN)

// ws float offsets (tiny, safe for any ws_size)
#define WS_ENORM  0
#define WS_CNT    1024
#define WS_LOSS   2048
#define WS_RC     2049
#define WS_RC2    2050       // hard count
#define WS_LIST   2051       // [32768]
#define WS_SMOOTH 34819

#define REF_CAP 32768
#define DELTA   0.25f
#define MARGIN  0.03f        // fp32 top-2 gap below which we go exact fp64
#define RT      16           // refine tokens per block-batch

typedef __attribute__((ext_vector_type(8))) short bf16x8;
typedef __attribute__((ext_vector_type(4))) float f32x4;

__device__ __forceinline__ u16 bf16_rne(float f) {
    unsigned int u = __float_as_uint(f);
    unsigned int r = u + 0x7FFF + ((u >> 16) & 1);
    return (u16)(r >> 16);
}
__device__ __forceinline__ float bf16_to_f(u16 s) {
    return __uint_as_float(((unsigned int)s) << 16);
}
__device__ __forceinline__ void gload_lds16(const void* g, void* l) {
    __builtin_amdgcn_global_load_lds(
        (const __attribute__((address_space(1))) unsigned int*)g,
        (__attribute__((address_space(3))) unsigned int*)l, 16, 0, 0);
}

// ---------------------------------------------------------------- ||e_k||^2
__global__ void k_enorm(const float* __restrict__ embed, float* __restrict__ enorm,
                        double* __restrict__ enorm64) {
    int k = blockIdx.x * 256 + threadIdx.x;
    double s = 0.0;
    for (int d = 0; d < DIM; ++d) {
        float e = embed[(size_t)d * NCODE + k];
        s += (double)e * (double)e;
    }
    enorm[k] = (float)s;
    enorm64[k] = s;
}

// ------------------- k_xs: x [b][d][hw] fp32 -> Xs [n][256] bf16 (transpose) + sum(x^2)
__global__ __launch_bounds__(256) void k_xs(const float* __restrict__ x,
                                            u16* __restrict__ Xs,
                                            float* __restrict__ loss_acc)
{
    __shared__ float tile[64 * 65];
    __shared__ float red[256];
    const int tid = threadIdx.x;
    const int blk = blockIdx.x;          // 8192 = 32 b x 4 dc x 64 hwc
    const int b = blk >> 8;
    const int dc = (blk >> 6) & 3;
    const int hwc = blk & 63;
    const int d0 = dc * 64, hw0 = hwc * 64;
    const int r = tid >> 2, s = tid & 3;
    float sq = 0.f;
#pragma unroll
    for (int j = 0; j < 4; ++j) {
        float4 v = *(const float4*)&x[(size_t)b * PLANE + (size_t)(d0 + r) * HW + hw0 + s * 16 + j * 4];
        int c = s * 16 + j * 4;
        tile[r * 65 + c + 0] = v.x; tile[r * 65 + c + 1] = v.y;
        tile[r * 65 + c + 2] = v.z; tile[r * 65 + c + 3] = v.w;
        sq = fmaf(v.x, v.x, sq); sq = fmaf(v.y, v.y, sq);
        sq = fmaf(v.z, v.z, sq); sq = fmaf(v.w, v.w, sq);
    }
    __syncthreads();
    const int tk = tid >> 2, dq = tid & 3;
    u16 us[16];
#pragma unroll
    for (int j = 0; j < 16; ++j)
        us[j] = bf16_rne(tile[(dq * 16 + j) * 65 + tk]);
    size_t ob = (size_t)(b * 4096 + hw0 + tk) * 256 + d0 + dq * 16;
    *(uint4*)&Xs[ob]     = *(uint4*)&us[0];
    *(uint4*)&Xs[ob + 8] = *(uint4*)&us[8];
    red[tid] = sq; __syncthreads();
    for (int st = 128; st > 0; st >>= 1) {
        if (tid < st) red[tid] += red[tid + st];
        __syncthreads();
    }
    if (tid == 0) atomicAdd(loss_acc, red[0]);
}

// ------------------- k_bt: embed -> swizzled bf16 tiles Bt_sw[cc*16+kc][512 granules]
// kc 0..7 = E_hi rows (d = kc*32..), kc 8..15 = E_lo. Granule g of row n stored at slot (g+n)&3.
__global__ __launch_bounds__(256) void k_bt(const float* __restrict__ embed, u16* __restrict__ Bt)
{
    const int tile = blockIdx.x;          // 128 tiles
    const int cc = tile >> 4, kc = tile & 15;
    const int seg = kc >> 3, dbase = (kc & 7) * 32;
    const int tid = threadIdx.x;
#pragma unroll
    for (int g2 = 0; g2 < 2; ++g2) {
        int p = g2 * 256 + tid;
        int n = p >> 2, s = p & 3, lg = (s - n) & 3;
        int code = cc * 128 + n;
        u16 us[8];
#pragma unroll
        for (int e = 0; e < 8; ++e) {
            int d = dbase + lg * 8 + e;
            float E = embed[(size_t)d * NCODE + code];
            u16 hi = bf16_rne(E);
            us[e] = seg ? bf16_rne(E - bf16_to_f(hi)) : hi;
        }
        *(uint4*)&Bt[(size_t)tile * 4096 + (size_t)p * 8] = *(uint4*)&us[0];
    }
}

// ------------------- k_dist: bf16 MFMA GEMM (K=512) + per-chunk top-2  [round-2 proven]
__global__ __launch_bounds__(256) void k_dist(
    const u16* __restrict__ Xs, const u16* __restrict__ Bt,
    const float* __restrict__ enorm,
    float* __restrict__ pv1, float* __restrict__ pv2, float* __restrict__ pkk)
{
    __shared__ __align__(16) u16 lds[12288];   // A 8KB | B0 8KB | B1 8KB
    const int tid = threadIdx.x;
    const int w = tid >> 6, l = tid & 63;
    const int cc = blockIdx.x >> 10;
    const int n0 = (blockIdx.x & 1023) * 128;
    const int mh = w & 1, nh = w >> 1;
    const int lane15 = l & 15, quad = l >> 4;

    const u16* src[6];
    u16* dst[6];
#pragma unroll
    for (int r = 0; r < 6; ++r) {
        int p = r * 256 + w * 64 + l;
        dst[r] = &lds[(size_t)(r * 256 + w * 64) * 8];
        if (p < 512) {
            int m = p >> 2, s = p & 3, lg = (s - m) & 3;
            src[r] = Xs + (size_t)(n0 + m) * 256 + lg * 8;
        } else {
            int q = p - 512;
            int kcb = (q >> 9) * 8;
            int qq = q & 511;
            src[r] = Bt + (size_t)(cc * 16 + kcb) * 4096 + (size_t)qq * 8;
        }
    }

    f32x4 acc[4][4];
#pragma unroll
    for (int i = 0; i < 4; ++i)
#pragma unroll
        for (int j = 0; j < 4; ++j) acc[i][j] = (f32x4)0.f;

    for (int kc8 = 0; kc8 < 8; ++kc8) {
        __syncthreads();
#pragma unroll
        for (int r = 0; r < 6; ++r) {
            const u16* s = src[r] + (r < 2 ? (size_t)kc8 * 32 : (size_t)kc8 * 4096);
            gload_lds16(s, dst[r]);
        }
        __syncthreads();

        bf16x8 af[4];
#pragma unroll
        for (int mt = 0; mt < 4; ++mt) {
            int m = mh * 64 + mt * 16 + lane15;
            int slot = (quad + m) & 3;
            af[mt] = *(const bf16x8*)&lds[(size_t)(m * 4 + slot) * 8];
        }
#pragma unroll
        for (int seg = 0; seg < 2; ++seg) {
#pragma unroll
            for (int nt = 0; nt < 4; ++nt) {
                int n = nh * 64 + nt * 16 + lane15;
                int slot = (quad + n) & 3;
                bf16x8 bfr = *(const bf16x8*)&lds[(size_t)(512 + seg * 512 + n * 4 + slot) * 8];
#pragma unroll
                for (int mt = 0; mt < 4; ++mt)
                    acc[mt][nt] = __builtin_amdgcn_mfma_f32_16x16x32_bf16(af[mt], bfr, acc[mt][nt], 0, 0, 0);
            }
        }
    }

    float ev[4]; int ec[4];
#pragma unroll
    for (int nt = 0; nt < 4; ++nt) {
        ec[nt] = cc * 128 + nh * 64 + nt * 16 + lane15;
        ev[nt] = enorm[ec[nt]];
    }
    float r1[4][4], r2[4][4]; int rk[4][4];
#pragma unroll
    for (int mt = 0; mt < 4; ++mt)
#pragma unroll
        for (int rg = 0; rg < 4; ++rg) {
            float v1 = FLT_MAX, v2 = FLT_MAX; int k1 = 1 << 30;
#pragma unroll
            for (int nt = 0; nt < 4; ++nt) {
                float d = fmaf(-2.f, acc[mt][nt][rg], ev[nt]);
                if (d < v1) { v2 = v1; v1 = d; k1 = ec[nt]; }
                else v2 = fminf(v2, d);
            }
            r1[mt][rg] = v1; r2[mt][rg] = v2; rk[mt][rg] = k1;
        }
#pragma unroll
    for (int mask = 1; mask <= 8; mask <<= 1) {
#pragma unroll
        for (int mt = 0; mt < 4; ++mt)
#pragma unroll
            for (int rg = 0; rg < 4; ++rg) {
                float ov1 = __shfl_xor(r1[mt][rg], mask);
                float ov2 = __shfl_xor(r2[mt][rg], mask);
                int   ok  = __shfl_xor(rk[mt][rg], mask);
                if (ov1 < r1[mt][rg] || (ov1 == r1[mt][rg] && ok < rk[mt][rg])) {
                    r2[mt][rg] = fminf(r1[mt][rg], ov2);
                    r1[mt][rg] = ov1; rk[mt][rg] = ok;
                } else {
                    r2[mt][rg] = fminf(r2[mt][rg], ov1);
                }
            }
    }
    __syncthreads();
    float* epi = (float*)lds;   // [2 n-halves][128 tokens][3]
    if (lane15 == 0) {
#pragma unroll
        for (int mt = 0; mt < 4; ++mt)
#pragma unroll
            for (int rg = 0; rg < 4; ++rg) {
                int t = mh * 64 + mt * 16 + quad * 4 + rg;
                float* p = &epi[(nh * 128 + t) * 3];
                p[0] = r1[mt][rg]; p[1] = r2[mt][rg]; p[2] = __int_as_float(rk[mt][rg]);
            }
    }
    __syncthreads();
    if (tid < 128) {
        const float* p0 = &epi[tid * 3];
        const float* p1 = &epi[(128 + tid) * 3];
        float v1 = p0[0], v2 = p0[1]; int k1 = __float_as_int(p0[2]);
        float a1 = p1[0], a2 = p1[1]; int ak = __float_as_int(p1[2]);
        if (a1 < v1 || (a1 == v1 && ak < k1)) { v2 = fminf(v1, a2); v1 = a1; k1 = ak; }
        else v2 = fminf(v2, a1);
        size_t o = (size_t)cc * NTOK + n0 + tid;
        pv1[o] = v1; pv2[o] = v2; pkk[o] = (float)k1;
    }
}

// ------------------- k_amin: combine 8 chunk partials -> idx, vf, refine flags, sum(v1)
__global__ __launch_bounds__(256) void k_amin(
    const float* __restrict__ pv1, const float* __restrict__ pv2, const float* __restrict__ pkk,
    float* __restrict__ out_idx, float* __restrict__ vf, float* __restrict__ loss_acc,
    int* __restrict__ refcnt, int* __restrict__ reflist)
{
    const int n = blockIdx.x * 256 + threadIdx.x;
    float v1 = FLT_MAX, v2 = FLT_MAX; int k1 = 1 << 30;
    for (int cc = 0; cc < 8; ++cc) {
        float a1 = pv1[(size_t)cc * NTOK + n], a2 = pv2[(size_t)cc * NTOK + n];
        int ak = (int)pkk[(size_t)cc * NTOK + n];
        if (a1 < v1 || (a1 == v1 && ak < k1)) { v2 = fminf(v1, a2); v1 = a1; k1 = ak; }
        else v2 = fminf(v2, a1);
    }
    out_idx[n] = (float)k1;
    vf[n] = v1;
    if (v2 - v1 < DELTA) {
        int pos = atomicAdd(refcnt, 1);
        if (pos < REF_CAP) reflist[pos] = n;
    }
    __shared__ float red[256];
    red[threadIdx.x] = v1; __syncthreads();
    for (int s = 128; s > 0; s >>= 1) {
        if (threadIdx.x < s) red[threadIdx.x] += red[threadIdx.x + s];
        __syncthreads();
    }
    if (threadIdx.x == 0) atomicAdd(loss_acc, red[0]);
}

// ------------------- k_ref32: fp32 prefilter over flagged tokens
// dist_k = enorm[k] + sum_d e[d,k]*(-2x[d]) in fp32 (err <= ~2e-3).
// If fp32 top-2 gap > MARGIN: winner is provably the fp64 argmin -> commit.
// Else: push token to hardlist for exact fp64 pass (k_ref64).
__global__ __launch_bounds__(256) void k_ref32(
    const float* __restrict__ x, const float* __restrict__ embed,
    const float* __restrict__ enorm,
    float* __restrict__ out_idx, const int* __restrict__ refcnt,
    const int* __restrict__ reflist, const float* __restrict__ vf,
    float* __restrict__ loss_acc, int* __restrict__ hardcnt, int* __restrict__ hardlist)
{
    __shared__ float xm2t[DIM][RT + 1];   // [d][j] = -2*x, pad 17 -> conflict-free writes
    __shared__ int toks[RT];
    __shared__ float wv1[4][RT], wv2[4][RT];
    __shared__ int wk1[4][RT];
    const int tid = threadIdx.x;
    const int w = tid >> 6;
    const int cnt = min(*refcnt, REF_CAP);
    for (int base = blockIdx.x * RT; base < cnt; base += gridDim.x * RT) {
        const int nb = min(RT, cnt - base);
        for (int j = 0; j < nb; ++j) {
            int n = reflist[base + j];
            if (tid == 0) toks[j] = n;
            int b = n >> 12, hw = n & 4095;
            xm2t[tid][j] = -2.f * x[(size_t)b * PLANE + (size_t)tid * HW + hw];
        }
        if (nb < RT)
            for (int j = nb; j < RT; ++j) xm2t[tid][j] = 0.f;
        __syncthreads();

        float b1[RT], b2[RT]; int k1[RT];
#pragma unroll
        for (int j = 0; j < RT; ++j) { b1[j] = FLT_MAX; b2[j] = FLT_MAX; k1[j] = 1 << 30; }
#pragma unroll 1
        for (int c = 0; c < 4; ++c) {
            const int k = c * 256 + tid;
            float acc[RT];
#pragma unroll
            for (int j = 0; j < RT; ++j) acc[j] = 0.f;
#pragma unroll 1
            for (int d0 = 0; d0 < DIM; d0 += 8) {
                float er[8];
#pragma unroll
                for (int dd = 0; dd < 8; ++dd)
                    er[dd] = embed[(size_t)(d0 + dd) * NCODE + k];
#pragma unroll
                for (int dd = 0; dd < 8; ++dd)
#pragma unroll
                    for (int j = 0; j < RT; ++j)
                        acc[j] = fmaf(er[dd], xm2t[d0 + dd][j], acc[j]);
            }
            float e2 = enorm[k];
#pragma unroll
            for (int j = 0; j < RT; ++j) {
                float dist = e2 + acc[j];
                if (dist < b1[j]) { b2[j] = b1[j]; b1[j] = dist; k1[j] = k; }
                else b2[j] = fminf(b2[j], dist);
            }
        }

        // wave top-2 merge, then cross-wave
#pragma unroll
        for (int m = 1; m < 64; m <<= 1) {
#pragma unroll
            for (int j = 0; j < RT; ++j) {
                float ov1 = __shfl_xor(b1[j], m);
                float ov2 = __shfl_xor(b2[j], m);
                int   ok  = __shfl_xor(k1[j], m);
                if (ov1 < b1[j] || (ov1 == b1[j] && ok < k1[j])) {
                    b2[j] = fminf(b1[j], ov2); b1[j] = ov1; k1[j] = ok;
                } else {
                    b2[j] = fminf(b2[j], ov1);
                }
            }
        }
        if ((tid & 63) == 0) {
#pragma unroll
            for (int j = 0; j < RT; ++j) { wv1[w][j] = b1[j]; wk1[w][j] = k1[j]; wv2[w][j] = b2[j]; }
        }
        __syncthreads();
        if (tid < nb) {
            float v1 = wv1[0][tid], v2 = wv2[0][tid]; int kk = wk1[0][tid];
#pragma unroll
            for (int wi = 1; wi < 4; ++wi) {
                float a1 = wv1[wi][tid], a2 = wv2[wi][tid]; int ak = wk1[wi][tid];
                if (a1 < v1 || (a1 == v1 && ak < kk)) { v2 = fminf(v1, a2); v1 = a1; kk = ak; }
                else v2 = fminf(v2, a1);
            }
            int n = toks[tid];
            if (v2 - v1 > MARGIN) {
                out_idx[n] = (float)kk;
                atomicAdd(loss_acc, v1 - vf[n]);
            } else {
                int pos = atomicAdd(hardcnt, 1);
                hardlist[pos] = n;
            }
        }
        __syncthreads();
    }
}

// ------------------- k_ref64: exact fp64 argmin (v2 code) over hard tokens
__global__ __launch_bounds__(256) void k_ref64(
    const float* __restrict__ x, const float* __restrict__ embed,
    const double* __restrict__ enorm64,
    float* __restrict__ out_idx, const int* __restrict__ hcnt,
    const int* __restrict__ hlist, const float* __restrict__ vf,
    float* __restrict__ loss_acc)
{
    __shared__ double xm2[RT][DIM];     // -2*x per token (32 KB)
    __shared__ int toks[RT];
    __shared__ double wv[4][RT];
    __shared__ int wk[4][RT];
    const int tid = threadIdx.x;
    const int w = tid >> 6, l = tid & 63;
    const int cnt = min(*hcnt, REF_CAP);
    for (int base = blockIdx.x * RT; base < cnt; base += gridDim.x * RT) {
        const int nb = min(RT, cnt - base);
        for (int j = 0; j < nb; ++j) {
            int n = hlist[base + j];
            if (tid == 0) toks[j] = n;
            int b = n >> 12, hw = n & 4095;
            float xv = x[(size_t)b * PLANE + (size_t)tid * HW + hw];
            xm2[j][tid] = -2.0 * (double)xv;
        }
        __syncthreads();

        double bv[RT]; int bk[RT];
#pragma unroll
        for (int j = 0; j < RT; ++j) { bv[j] = 1e300; bk[j] = 0; }
#pragma unroll 1
        for (int c = 0; c < 4; ++c) {
            const int k = c * 256 + tid;
            double acc[RT];
#pragma unroll
            for (int j = 0; j < RT; ++j) acc[j] = 0.0;
            const float* ep = embed + k;
#pragma unroll 4
            for (int d = 0; d < DIM; ++d) {
                double ed = (double)ep[(size_t)d * NCODE];
#pragma unroll
                for (int j = 0; j < RT; ++j)
                    acc[j] = fma(ed, xm2[j][d], acc[j]);
            }
            double e2 = enorm64[k];
#pragma unroll
            for (int j = 0; j < RT; ++j) {
                double dist = e2 + acc[j];
                if (dist < bv[j]) { bv[j] = dist; bk[j] = k; }
            }
        }

#pragma unroll
        for (int j = 0; j < RT; ++j) {
            double v = bv[j]; int kk = bk[j];
#pragma unroll
            for (int m = 1; m < 64; m <<= 1) {
                double ov = __shfl_xor(v, m);
                int ok = __shfl_xor(kk, m);
                if (ov < v || (ov == v && ok < kk)) { v = ov; kk = ok; }
            }
            if (l == 0) { wv[w][j] = v; wk[w][j] = kk; }
        }
        __syncthreads();
        if (tid < nb) {
            double v = wv[0][tid]; int kk = wk[0][tid];
#pragma unroll
            for (int wi = 1; wi < 4; ++wi) {
                double ov = wv[wi][tid]; int ok = wk[wi][tid];
                if (ov < v || (ov == v && ok < kk)) { v = ov; kk = ok; }
            }
            int n = toks[tid];
            out_idx[n] = (float)kk;
            atomicAdd(loss_acc, (float)(v - (double)vf[n]));
        }
        __syncthreads();
    }
}

// ------------------- k_cnt: ref_count (post-refine)
__global__ __launch_bounds__(256) void k_cnt(const float* __restrict__ out_idx, float* __restrict__ cnt) {
    const int n = blockIdx.x * 256 + threadIdx.x;
    atomicAdd(&cnt[(int)out_idx[n]], 1.0f);
}

// ------------------- k_dw: dw segment-sum via LDS tiles (nc=8 fixed)
__global__ __launch_bounds__(256) void k_dw(
    const float* __restrict__ x, const float* __restrict__ out_idx, float* __restrict__ part)
{
    __shared__ float tile[NCODE * 9];
    const int tid = threadIdx.x;
    const int slice = blockIdx.x & 31;
    const int chunk = blockIdx.x >> 5;
    const int d0 = slice * 8;
    for (int i = tid; i < NCODE * 9; i += 256) tile[i] = 0.f;
    __syncthreads();
    const int nbeg = chunk * (NTOK / 8);
    for (int t = tid; t < NTOK / 8; t += 256) {
        const int n = nbeg + t;
        const int b = n >> 12, hw = n & 4095;
        const int k = (int)out_idx[n];
        const float* xb = x + (size_t)b * PLANE + hw;
        float* tp = tile + k * 9;
#pragma unroll
        for (int dl = 0; dl < 8; ++dl)
            unsafeAtomicAdd(&tp[dl], xb[(size_t)(d0 + dl) * HW]);
    }
    __syncthreads();
    for (int i = tid; i < 8 * NCODE; i += 256) {
        const int dl = i >> 10, k = i & (NCODE - 1);
        part[((size_t)chunk * DIM + d0 + dl) * NCODE + k] = tile[k * 9 + dl];
    }
}

// ------------------- k_fin_cs: new_cluster_size + smoothing
__global__ __launch_bounds__(1024) void k_fin_cs(
    const float* __restrict__ cs_in, const float* __restrict__ cnt,
    float* __restrict__ out_ncs, float* __restrict__ smooth)
{
    const int k = threadIdx.x;
    float ncs = cs_in[k] * DECAYF + (1.f - DECAYF) * cnt[k];
    out_ncs[k] = ncs;
    __shared__ float red[1024];
    red[k] = ncs; __syncthreads();
    for (int s = 512; s > 0; s >>= 1) {
        if (k < s) red[k] += red[k + s];
        __syncthreads();
    }
    float n = red[0];
    smooth[k] = n * ((ncs + EPSF) / (n + ncs * EPSF));
}

// ------------------- k_fin_emb: sum dw partials, new_ema_embed, new_embed
__global__ __launch_bounds__(256) void k_fin_emb(
    const float* __restrict__ ema, const float* __restrict__ part,
    const float* __restrict__ smooth, float* __restrict__ out_ne, float* __restrict__ out_nee)
{
    const int i = blockIdx.x * 256 + threadIdx.x;
    const int k = i & (NCODE - 1);
    float dw = 0.f;
    for (int c = 0; c < 8; ++c) dw += part[(size_t)c * (DIM * NCODE) + i];
    float nee = ema[i] * DECAYF + (1.f - DECAYF) * dw;
    out_nee[i] = nee;
    out_ne[i] = nee / smooth[k];
}

// ------------------- k_quant: pure gather write (runs LAST, overwrites scratch)
__global__ __launch_bounds__(256) void k_quant(
    const float* __restrict__ embed, const float* __restrict__ out_idx, float* __restrict__ out_q)
{
    const int n = blockIdx.x * 256 + threadIdx.x;
    const int b = n >> 12, hw = n & 4095;
    const int idx = (int)out_idx[n];
    const size_t base = (size_t)b * PLANE + hw;
    for (int d = 0; d < DIM; ++d)
        out_q[base + (size_t)d * HW] = embed[(size_t)d * NCODE + idx];
}

// ------------------- k_loss: finalize scalar
__global__ void k_loss(const float* __restrict__ loss_acc, float* __restrict__ out_loss) {
    out_loss[0] = 0.25f * loss_acc[0] / 33554432.f;
}

extern "C" void kernel_launch(void* const* d_in, const int* in_sizes, int n_in,
                              void* d_out, int out_size, void* d_ws, size_t ws_size,
                              hipStream_t stream) {
    const float* x     = (const float*)d_in[0];
    const float* embed = (const float*)d_in[1];
    const float* csz   = (const float*)d_in[2];
    const float* ema   = (const float*)d_in[3];
    float* out = (float*)d_out;
    float* ws  = (float*)d_ws;

    u16* Xs = (u16*)(out + P_XS);
    u16* Bt = (u16*)(out + P_BT);
    double* enorm64 = (double*)(out + P_ENORM64);

    // zero cnt[1024], loss, refcnt, hardcnt
    hipMemsetAsync(ws + WS_CNT, 0, (size_t)(WS_RC2 + 1 - WS_CNT) * sizeof(float), stream);

    k_enorm<<<4, 256, 0, stream>>>(embed, ws + WS_ENORM, enorm64);
    k_xs<<<8192, 256, 0, stream>>>(x, Xs, ws + WS_LOSS);
    k_bt<<<128, 256, 0, stream>>>(embed, Bt);
    k_dist<<<8192, 256, 0, stream>>>(Xs, Bt, ws + WS_ENORM,
                                     out + P_V1, out + P_V2, out + P_KK);
    k_amin<<<NTOK / 256, 256, 0, stream>>>(out + P_V1, out + P_V2, out + P_KK,
                                           out + O_IDX, out + P_VF, ws + WS_LOSS,
                                           (int*)(ws + WS_RC), (int*)(ws + WS_LIST));
    k_ref32<<<2048, 256, 0, stream>>>(x, embed, ws + WS_ENORM, out + O_IDX,
                                      (const int*)(ws + WS_RC), (const int*)(ws + WS_LIST),
                                      out + P_VF, ws + WS_LOSS,
                                      (int*)(ws + WS_RC2), (int*)(out + P_HLIST));
    k_ref64<<<512, 256, 0, stream>>>(x, embed, enorm64, out + O_IDX,
                                     (const int*)(ws + WS_RC2), (const int*)(out + P_HLIST),
                                     out + P_VF, ws + WS_LOSS);
    k_cnt<<<NTOK / 256, 256, 0, stream>>>(out + O_IDX, ws + WS_CNT);
    k_dw<<<256, 256, 0, stream>>>(x, out + O_IDX, out + P_DW);
    k_fin_cs<<<1, 1024, 0, stream>>>(csz, ws + WS_CNT, out + O_NCS, ws + WS_SMOOTH);
    k_fin_emb<<<1024, 256, 0, stream>>>(ema, out + P_DW, ws + WS_SMOOTH,
                                        out + O_NEWEMB, out + O_NEE);
    k_quant<<<NTOK / 256, 256, 0, stream>>>(embed, out + O_IDX, out + O_OUT);
    k_loss<<<1, 1, 0, stream>>>(ws + WS_LOSS, out + O_LOSS);
}

// Round 6
// 1150.879 us; speedup vs baseline: 1.1325x; 1.1052x over previous
//
#include <hip/hip_runtime.h>
#include <cfloat>
#include <cstdint>

typedef unsigned short u16;

// Problem constants
#define NTOK   131072      // B*H*W
#define DIM    256
#define NCODE  1024
#define HW     4096
#define PLANE  1048576     // DIM*HW
#define DECAYF 0.9f
#define EPSF   1e-5f

// d_out float offsets (outputs concatenated in return order)
#define O_OUT     0
#define O_LOSS    33554432
#define O_IDX     33554433
#define O_NEWEMB  33685505
#define O_NCS     33947649
#define O_NEE     33948673

// scratch regions INSIDE O_OUT (float offsets) — k_quant overwrites O_OUT last
#define P_XS      0          // Xs bf16 [131072][256]
#define P_V1      16777216   // [8][131072]
#define P_V2      17825792
#define P_KK      18874368
#define P_VF      19922944   // [131072] final approx v1
#define P_DW      20054016   // [8][262144] dw partials
#define P_BT      22151168   // Bt_sw swizzled tiles, 1 MB
#define P_ENORM64 22413312   // [1024] doubles (2048 floats), byte-offset %8 == 0
#define P_HLIST   22415360   // [32768] ints: hard-token list (fp32 gap <= MARGIN)

// ws float offsets (tiny, safe for any ws_size)
#define WS_ENORM  0
#define WS_CNT    1024
#define WS_LOSS   2048
#define WS_RC     2049
#define WS_RC2    2050       // hard count
#define WS_LIST   2051       // [32768]
#define WS_SMOOTH 34819

#define REF_CAP 32768
#define DELTA   0.25f
#define MARGIN  0.03f        // fp32 top-2 gap below which we go exact fp64
#define RT      16           // refine tokens per block-batch (k_ref32 only)

typedef __attribute__((ext_vector_type(8))) short bf16x8;
typedef __attribute__((ext_vector_type(4))) float f32x4;

__device__ __forceinline__ u16 bf16_rne(float f) {
    unsigned int u = __float_as_uint(f);
    unsigned int r = u + 0x7FFF + ((u >> 16) & 1);
    return (u16)(r >> 16);
}
__device__ __forceinline__ float bf16_to_f(u16 s) {
    return __uint_as_float(((unsigned int)s) << 16);
}
__device__ __forceinline__ void gload_lds16(const void* g, void* l) {
    __builtin_amdgcn_global_load_lds(
        (const __attribute__((address_space(1))) unsigned int*)g,
        (__attribute__((address_space(3))) unsigned int*)l, 16, 0, 0);
}

// ---------------------------------------------------------------- ||e_k||^2
__global__ void k_enorm(const float* __restrict__ embed, float* __restrict__ enorm,
                        double* __restrict__ enorm64) {
    int k = blockIdx.x * 256 + threadIdx.x;
    double s = 0.0;
    for (int d = 0; d < DIM; ++d) {
        float e = embed[(size_t)d * NCODE + k];
        s += (double)e * (double)e;
    }
    enorm[k] = (float)s;
    enorm64[k] = s;
}

// ------------------- k_xs: x [b][d][hw] fp32 -> Xs [n][256] bf16 (transpose) + sum(x^2)
__global__ __launch_bounds__(256) void k_xs(const float* __restrict__ x,
                                            u16* __restrict__ Xs,
                                            float* __restrict__ loss_acc)
{
    __shared__ float tile[64 * 65];
    __shared__ float red[256];
    const int tid = threadIdx.x;
    const int blk = blockIdx.x;          // 8192 = 32 b x 4 dc x 64 hwc
    const int b = blk >> 8;
    const int dc = (blk >> 6) & 3;
    const int hwc = blk & 63;
    const int d0 = dc * 64, hw0 = hwc * 64;
    const int r = tid >> 2, s = tid & 3;
    float sq = 0.f;
#pragma unroll
    for (int j = 0; j < 4; ++j) {
        float4 v = *(const float4*)&x[(size_t)b * PLANE + (size_t)(d0 + r) * HW + hw0 + s * 16 + j * 4];
        int c = s * 16 + j * 4;
        tile[r * 65 + c + 0] = v.x; tile[r * 65 + c + 1] = v.y;
        tile[r * 65 + c + 2] = v.z; tile[r * 65 + c + 3] = v.w;
        sq = fmaf(v.x, v.x, sq); sq = fmaf(v.y, v.y, sq);
        sq = fmaf(v.z, v.z, sq); sq = fmaf(v.w, v.w, sq);
    }
    __syncthreads();
    const int tk = tid >> 2, dq = tid & 3;
    u16 us[16];
#pragma unroll
    for (int j = 0; j < 16; ++j)
        us[j] = bf16_rne(tile[(dq * 16 + j) * 65 + tk]);
    size_t ob = (size_t)(b * 4096 + hw0 + tk) * 256 + d0 + dq * 16;
    *(uint4*)&Xs[ob]     = *(uint4*)&us[0];
    *(uint4*)&Xs[ob + 8] = *(uint4*)&us[8];
    red[tid] = sq; __syncthreads();
    for (int st = 128; st > 0; st >>= 1) {
        if (tid < st) red[tid] += red[tid + st];
        __syncthreads();
    }
    if (tid == 0) atomicAdd(loss_acc, red[0]);
}

// ------------------- k_bt: embed -> swizzled bf16 tiles Bt_sw[cc*16+kc][512 granules]
// kc 0..7 = E_hi rows (d = kc*32..), kc 8..15 = E_lo. Granule g of row n stored at slot (g+n)&3.
__global__ __launch_bounds__(256) void k_bt(const float* __restrict__ embed, u16* __restrict__ Bt)
{
    const int tile = blockIdx.x;          // 128 tiles
    const int cc = tile >> 4, kc = tile & 15;
    const int seg = kc >> 3, dbase = (kc & 7) * 32;
    const int tid = threadIdx.x;
#pragma unroll
    for (int g2 = 0; g2 < 2; ++g2) {
        int p = g2 * 256 + tid;
        int n = p >> 2, s = p & 3, lg = (s - n) & 3;
        int code = cc * 128 + n;
        u16 us[8];
#pragma unroll
        for (int e = 0; e < 8; ++e) {
            int d = dbase + lg * 8 + e;
            float E = embed[(size_t)d * NCODE + code];
            u16 hi = bf16_rne(E);
            us[e] = seg ? bf16_rne(E - bf16_to_f(hi)) : hi;
        }
        *(uint4*)&Bt[(size_t)tile * 4096 + (size_t)p * 8] = *(uint4*)&us[0];
    }
}

// ------------------- k_dist: bf16 MFMA GEMM (K=512) + per-chunk top-2  [round-2 proven]
__global__ __launch_bounds__(256) void k_dist(
    const u16* __restrict__ Xs, const u16* __restrict__ Bt,
    const float* __restrict__ enorm,
    float* __restrict__ pv1, float* __restrict__ pv2, float* __restrict__ pkk)
{
    __shared__ __align__(16) u16 lds[12288];   // A 8KB | B0 8KB | B1 8KB
    const int tid = threadIdx.x;
    const int w = tid >> 6, l = tid & 63;
    const int cc = blockIdx.x >> 10;
    const int n0 = (blockIdx.x & 1023) * 128;
    const int mh = w & 1, nh = w >> 1;
    const int lane15 = l & 15, quad = l >> 4;

    const u16* src[6];
    u16* dst[6];
#pragma unroll
    for (int r = 0; r < 6; ++r) {
        int p = r * 256 + w * 64 + l;
        dst[r] = &lds[(size_t)(r * 256 + w * 64) * 8];
        if (p < 512) {
            int m = p >> 2, s = p & 3, lg = (s - m) & 3;
            src[r] = Xs + (size_t)(n0 + m) * 256 + lg * 8;
        } else {
            int q = p - 512;
            int kcb = (q >> 9) * 8;
            int qq = q & 511;
            src[r] = Bt + (size_t)(cc * 16 + kcb) * 4096 + (size_t)qq * 8;
        }
    }

    f32x4 acc[4][4];
#pragma unroll
    for (int i = 0; i < 4; ++i)
#pragma unroll
        for (int j = 0; j < 4; ++j) acc[i][j] = (f32x4)0.f;

    for (int kc8 = 0; kc8 < 8; ++kc8) {
        __syncthreads();
#pragma unroll
        for (int r = 0; r < 6; ++r) {
            const u16* s = src[r] + (r < 2 ? (size_t)kc8 * 32 : (size_t)kc8 * 4096);
            gload_lds16(s, dst[r]);
        }
        __syncthreads();

        bf16x8 af[4];
#pragma unroll
        for (int mt = 0; mt < 4; ++mt) {
            int m = mh * 64 + mt * 16 + lane15;
            int slot = (quad + m) & 3;
            af[mt] = *(const bf16x8*)&lds[(size_t)(m * 4 + slot) * 8];
        }
#pragma unroll
        for (int seg = 0; seg < 2; ++seg) {
#pragma unroll
            for (int nt = 0; nt < 4; ++nt) {
                int n = nh * 64 + nt * 16 + lane15;
                int slot = (quad + n) & 3;
                bf16x8 bfr = *(const bf16x8*)&lds[(size_t)(512 + seg * 512 + n * 4 + slot) * 8];
#pragma unroll
                for (int mt = 0; mt < 4; ++mt)
                    acc[mt][nt] = __builtin_amdgcn_mfma_f32_16x16x32_bf16(af[mt], bfr, acc[mt][nt], 0, 0, 0);
            }
        }
    }

    float ev[4]; int ec[4];
#pragma unroll
    for (int nt = 0; nt < 4; ++nt) {
        ec[nt] = cc * 128 + nh * 64 + nt * 16 + lane15;
        ev[nt] = enorm[ec[nt]];
    }
    float r1[4][4], r2[4][4]; int rk[4][4];
#pragma unroll
    for (int mt = 0; mt < 4; ++mt)
#pragma unroll
        for (int rg = 0; rg < 4; ++rg) {
            float v1 = FLT_MAX, v2 = FLT_MAX; int k1 = 1 << 30;
#pragma unroll
            for (int nt = 0; nt < 4; ++nt) {
                float d = fmaf(-2.f, acc[mt][nt][rg], ev[nt]);
                if (d < v1) { v2 = v1; v1 = d; k1 = ec[nt]; }
                else v2 = fminf(v2, d);
            }
            r1[mt][rg] = v1; r2[mt][rg] = v2; rk[mt][rg] = k1;
        }
#pragma unroll
    for (int mask = 1; mask <= 8; mask <<= 1) {
#pragma unroll
        for (int mt = 0; mt < 4; ++mt)
#pragma unroll
            for (int rg = 0; rg < 4; ++rg) {
                float ov1 = __shfl_xor(r1[mt][rg], mask);
                float ov2 = __shfl_xor(r2[mt][rg], mask);
                int   ok  = __shfl_xor(rk[mt][rg], mask);
                if (ov1 < r1[mt][rg] || (ov1 == r1[mt][rg] && ok < rk[mt][rg])) {
                    r2[mt][rg] = fminf(r1[mt][rg], ov2);
                    r1[mt][rg] = ov1; rk[mt][rg] = ok;
                } else {
                    r2[mt][rg] = fminf(r2[mt][rg], ov1);
                }
            }
    }
    __syncthreads();
    float* epi = (float*)lds;   // [2 n-halves][128 tokens][3]
    if (lane15 == 0) {
#pragma unroll
        for (int mt = 0; mt < 4; ++mt)
#pragma unroll
            for (int rg = 0; rg < 4; ++rg) {
                int t = mh * 64 + mt * 16 + quad * 4 + rg;
                float* p = &epi[(nh * 128 + t) * 3];
                p[0] = r1[mt][rg]; p[1] = r2[mt][rg]; p[2] = __int_as_float(rk[mt][rg]);
            }
    }
    __syncthreads();
    if (tid < 128) {
        const float* p0 = &epi[tid * 3];
        const float* p1 = &epi[(128 + tid) * 3];
        float v1 = p0[0], v2 = p0[1]; int k1 = __float_as_int(p0[2]);
        float a1 = p1[0], a2 = p1[1]; int ak = __float_as_int(p1[2]);
        if (a1 < v1 || (a1 == v1 && ak < k1)) { v2 = fminf(v1, a2); v1 = a1; k1 = ak; }
        else v2 = fminf(v2, a1);
        size_t o = (size_t)cc * NTOK + n0 + tid;
        pv1[o] = v1; pv2[o] = v2; pkk[o] = (float)k1;
    }
}

// ------------------- k_amin: combine 8 chunk partials -> idx, vf, refine flags, sum(v1)
__global__ __launch_bounds__(256) void k_amin(
    const float* __restrict__ pv1, const float* __restrict__ pv2, const float* __restrict__ pkk,
    float* __restrict__ out_idx, float* __restrict__ vf, float* __restrict__ loss_acc,
    int* __restrict__ refcnt, int* __restrict__ reflist)
{
    const int n = blockIdx.x * 256 + threadIdx.x;
    float v1 = FLT_MAX, v2 = FLT_MAX; int k1 = 1 << 30;
    for (int cc = 0; cc < 8; ++cc) {
        float a1 = pv1[(size_t)cc * NTOK + n], a2 = pv2[(size_t)cc * NTOK + n];
        int ak = (int)pkk[(size_t)cc * NTOK + n];
        if (a1 < v1 || (a1 == v1 && ak < k1)) { v2 = fminf(v1, a2); v1 = a1; k1 = ak; }
        else v2 = fminf(v2, a1);
    }
    out_idx[n] = (float)k1;
    vf[n] = v1;
    if (v2 - v1 < DELTA) {
        int pos = atomicAdd(refcnt, 1);
        if (pos < REF_CAP) reflist[pos] = n;
    }
    __shared__ float red[256];
    red[threadIdx.x] = v1; __syncthreads();
    for (int s = 128; s > 0; s >>= 1) {
        if (threadIdx.x < s) red[threadIdx.x] += red[threadIdx.x + s];
        __syncthreads();
    }
    if (threadIdx.x == 0) atomicAdd(loss_acc, red[0]);
}

// ------------------- k_ref32: fp32 prefilter over flagged tokens (RT-batched; grid saturated)
__global__ __launch_bounds__(256) void k_ref32(
    const float* __restrict__ x, const float* __restrict__ embed,
    const float* __restrict__ enorm,
    float* __restrict__ out_idx, const int* __restrict__ refcnt,
    const int* __restrict__ reflist, const float* __restrict__ vf,
    float* __restrict__ loss_acc, int* __restrict__ hardcnt, int* __restrict__ hardlist)
{
    __shared__ float xm2t[DIM][RT + 1];   // [d][j] = -2*x, pad 17 -> conflict-free writes
    __shared__ int toks[RT];
    __shared__ float wv1[4][RT], wv2[4][RT];
    __shared__ int wk1[4][RT];
    const int tid = threadIdx.x;
    const int w = tid >> 6;
    const int cnt = min(*refcnt, REF_CAP);
    for (int base = blockIdx.x * RT; base < cnt; base += gridDim.x * RT) {
        const int nb = min(RT, cnt - base);
        for (int j = 0; j < nb; ++j) {
            int n = reflist[base + j];
            if (tid == 0) toks[j] = n;
            int b = n >> 12, hw = n & 4095;
            xm2t[tid][j] = -2.f * x[(size_t)b * PLANE + (size_t)tid * HW + hw];
        }
        if (nb < RT)
            for (int j = nb; j < RT; ++j) xm2t[tid][j] = 0.f;
        __syncthreads();

        float b1[RT], b2[RT]; int k1[RT];
#pragma unroll
        for (int j = 0; j < RT; ++j) { b1[j] = FLT_MAX; b2[j] = FLT_MAX; k1[j] = 1 << 30; }
#pragma unroll 1
        for (int c = 0; c < 4; ++c) {
            const int k = c * 256 + tid;
            float acc[RT];
#pragma unroll
            for (int j = 0; j < RT; ++j) acc[j] = 0.f;
#pragma unroll 1
            for (int d0 = 0; d0 < DIM; d0 += 8) {
                float er[8];
#pragma unroll
                for (int dd = 0; dd < 8; ++dd)
                    er[dd] = embed[(size_t)(d0 + dd) * NCODE + k];
#pragma unroll
                for (int dd = 0; dd < 8; ++dd)
#pragma unroll
                    for (int j = 0; j < RT; ++j)
                        acc[j] = fmaf(er[dd], xm2t[d0 + dd][j], acc[j]);
            }
            float e2 = enorm[k];
#pragma unroll
            for (int j = 0; j < RT; ++j) {
                float dist = e2 + acc[j];
                if (dist < b1[j]) { b2[j] = b1[j]; b1[j] = dist; k1[j] = k; }
                else b2[j] = fminf(b2[j], dist);
            }
        }

        // wave top-2 merge, then cross-wave
#pragma unroll
        for (int m = 1; m < 64; m <<= 1) {
#pragma unroll
            for (int j = 0; j < RT; ++j) {
                float ov1 = __shfl_xor(b1[j], m);
                float ov2 = __shfl_xor(b2[j], m);
                int   ok  = __shfl_xor(k1[j], m);
                if (ov1 < b1[j] || (ov1 == b1[j] && ok < k1[j])) {
                    b2[j] = fminf(b1[j], ov2); b1[j] = ov1; k1[j] = ok;
                } else {
                    b2[j] = fminf(b2[j], ov1);
                }
            }
        }
        if ((tid & 63) == 0) {
#pragma unroll
            for (int j = 0; j < RT; ++j) { wv1[w][j] = b1[j]; wk1[w][j] = k1[j]; wv2[w][j] = b2[j]; }
        }
        __syncthreads();
        if (tid < nb) {
            float v1 = wv1[0][tid], v2 = wv2[0][tid]; int kk = wk1[0][tid];
#pragma unroll
            for (int wi = 1; wi < 4; ++wi) {
                float a1 = wv1[wi][tid], a2 = wv2[wi][tid]; int ak = wk1[wi][tid];
                if (a1 < v1 || (a1 == v1 && ak < kk)) { v2 = fminf(v1, a2); v1 = a1; kk = ak; }
                else v2 = fminf(v2, a1);
            }
            int n = toks[tid];
            if (v2 - v1 > MARGIN) {
                out_idx[n] = (float)kk;
                atomicAdd(loss_acc, v1 - vf[n]);
            } else {
                int pos = atomicAdd(hardcnt, 1);
                hardlist[pos] = n;
            }
        }
        __syncthreads();
    }
}

// ------------------- k_ref64 v3: exact fp64 argmin, ONE BLOCK PER HARD TOKEN.
// Hard-token count is tiny (~hundreds): the RT-batched form left ~22 blocks on
// the whole GPU, each latency-serialized on ds_read->fp64-FMA pairs (310 us,
// VALUBusy 1%). Per-token blocks give cnt-way parallelism with a short
// per-token chain (~4 us). dist = enorm64[k] - 2*dot(e,x): exactly equal to the
// previous fma(e,-2x) formulation (x2 scaling commutes with rounding).
__global__ __launch_bounds__(256) void k_ref64(
    const float* __restrict__ x, const float* __restrict__ embed,
    const double* __restrict__ enorm64,
    float* __restrict__ out_idx, const int* __restrict__ hcnt,
    const int* __restrict__ hlist, const float* __restrict__ vf,
    float* __restrict__ loss_acc)
{
    __shared__ float xs[DIM];
    __shared__ double wv[4];
    __shared__ int wk[4];
    const int tid = threadIdx.x;
    const int w = tid >> 6, l = tid & 63;
    const int cnt = min(*hcnt, REF_CAP);
    for (int it = blockIdx.x; it < cnt; it += gridDim.x) {
        const int n = hlist[it];
        const int b = n >> 12, hw = n & 4095;
        xs[tid] = x[(size_t)b * PLANE + (size_t)tid * HW + hw];
        __syncthreads();
        double bv = 1e300; int bk = 1 << 30;
#pragma unroll 1
        for (int c = 0; c < 4; ++c) {
            const int k = c * 256 + tid;
            const float* ep = embed + k;
            double acc = 0.0;
#pragma unroll 8
            for (int d = 0; d < DIM; ++d)
                acc = fma((double)ep[(size_t)d * NCODE], (double)xs[d], acc);
            double dist = enorm64[k] - 2.0 * acc;
            if (dist < bv) { bv = dist; bk = k; }   // k strictly increasing: tie keeps smaller k
        }
        // wave argmin reduce, then cross-wave via LDS
#pragma unroll
        for (int m = 1; m < 64; m <<= 1) {
            double ov = __shfl_xor(bv, m);
            int ok = __shfl_xor(bk, m);
            if (ov < bv || (ov == bv && ok < bk)) { bv = ov; bk = ok; }
        }
        if (l == 0) { wv[w] = bv; wk[w] = bk; }
        __syncthreads();
        if (tid == 0) {
            double v = wv[0]; int kk = wk[0];
#pragma unroll
            for (int wi = 1; wi < 4; ++wi) {
                if (wv[wi] < v || (wv[wi] == v && wk[wi] < kk)) { v = wv[wi]; kk = wk[wi]; }
            }
            out_idx[n] = (float)kk;
            atomicAdd(loss_acc, (float)(v - (double)vf[n]));
        }
        __syncthreads();   // protect xs before next token
    }
}

// ------------------- k_cnt: ref_count (post-refine)
__global__ __launch_bounds__(256) void k_cnt(const float* __restrict__ out_idx, float* __restrict__ cnt) {
    const int n = blockIdx.x * 256 + threadIdx.x;
    atomicAdd(&cnt[(int)out_idx[n]], 1.0f);
}

// ------------------- k_dw: dw segment-sum via LDS tiles (nc=8 fixed)
__global__ __launch_bounds__(256) void k_dw(
    const float* __restrict__ x, const float* __restrict__ out_idx, float* __restrict__ part)
{
    __shared__ float tile[NCODE * 9];
    const int tid = threadIdx.x;
    const int slice = blockIdx.x & 31;
    const int chunk = blockIdx.x >> 5;
    const int d0 = slice * 8;
    for (int i = tid; i < NCODE * 9; i += 256) tile[i] = 0.f;
    __syncthreads();
    const int nbeg = chunk * (NTOK / 8);
    for (int t = tid; t < NTOK / 8; t += 256) {
        const int n = nbeg + t;
        const int b = n >> 12, hw = n & 4095;
        const int k = (int)out_idx[n];
        const float* xb = x + (size_t)b * PLANE + hw;
        float* tp = tile + k * 9;
#pragma unroll
        for (int dl = 0; dl < 8; ++dl)
            unsafeAtomicAdd(&tp[dl], xb[(size_t)(d0 + dl) * HW]);
    }
    __syncthreads();
    for (int i = tid; i < 8 * NCODE; i += 256) {
        const int dl = i >> 10, k = i & (NCODE - 1);
        part[((size_t)chunk * DIM + d0 + dl) * NCODE + k] = tile[k * 9 + dl];
    }
}

// ------------------- k_fin_cs: new_cluster_size + smoothing
__global__ __launch_bounds__(1024) void k_fin_cs(
    const float* __restrict__ cs_in, const float* __restrict__ cnt,
    float* __restrict__ out_ncs, float* __restrict__ smooth)
{
    const int k = threadIdx.x;
    float ncs = cs_in[k] * DECAYF + (1.f - DECAYF) * cnt[k];
    out_ncs[k] = ncs;
    __shared__ float red[1024];
    red[k] = ncs; __syncthreads();
    for (int s = 512; s > 0; s >>= 1) {
        if (k < s) red[k] += red[k + s];
        __syncthreads();
    }
    float n = red[0];
    smooth[k] = n * ((ncs + EPSF) / (n + ncs * EPSF));
}

// ------------------- k_fin_emb: sum dw partials, new_ema_embed, new_embed
__global__ __launch_bounds__(256) void k_fin_emb(
    const float* __restrict__ ema, const float* __restrict__ part,
    const float* __restrict__ smooth, float* __restrict__ out_ne, float* __restrict__ out_nee)
{
    const int i = blockIdx.x * 256 + threadIdx.x;
    const int k = i & (NCODE - 1);
    float dw = 0.f;
    for (int c = 0; c < 8; ++c) dw += part[(size_t)c * (DIM * NCODE) + i];
    float nee = ema[i] * DECAYF + (1.f - DECAYF) * dw;
    out_nee[i] = nee;
    out_ne[i] = nee / smooth[k];
}

// ------------------- k_quant: pure gather write (runs LAST, overwrites scratch)
__global__ __launch_bounds__(256) void k_quant(
    const float* __restrict__ embed, const float* __restrict__ out_idx, float* __restrict__ out_q)
{
    const int n = blockIdx.x * 256 + threadIdx.x;
    const int b = n >> 12, hw = n & 4095;
    const int idx = (int)out_idx[n];
    const size_t base = (size_t)b * PLANE + hw;
    for (int d = 0; d < DIM; ++d)
        out_q[base + (size_t)d * HW] = embed[(size_t)d * NCODE + idx];
}

// ------------------- k_loss: finalize scalar
__global__ void k_loss(const float* __restrict__ loss_acc, float* __restrict__ out_loss) {
    out_loss[0] = 0.25f * loss_acc[0] / 33554432.f;
}

extern "C" void kernel_launch(void* const* d_in, const int* in_sizes, int n_in,
                              void* d_out, int out_size, void* d_ws, size_t ws_size,
                              hipStream_t stream) {
    const float* x     = (const float*)d_in[0];
    const float* embed = (const float*)d_in[1];
    const float* csz   = (const float*)d_in[2];
    const float* ema   = (const float*)d_in[3];
    float* out = (float*)d_out;
    float* ws  = (float*)d_ws;

    u16* Xs = (u16*)(out + P_XS);
    u16* Bt = (u16*)(out + P_BT);
    double* enorm64 = (double*)(out + P_ENORM64);

    // zero cnt[1024], loss, refcnt, hardcnt
    hipMemsetAsync(ws + WS_CNT, 0, (size_t)(WS_RC2 + 1 - WS_CNT) * sizeof(float), stream);

    k_enorm<<<4, 256, 0, stream>>>(embed, ws + WS_ENORM, enorm64);
    k_xs<<<8192, 256, 0, stream>>>(x, Xs, ws + WS_LOSS);
    k_bt<<<128, 256, 0, stream>>>(embed, Bt);
    k_dist<<<8192, 256, 0, stream>>>(Xs, Bt, ws + WS_ENORM,
                                     out + P_V1, out + P_V2, out + P_KK);
    k_amin<<<NTOK / 256, 256, 0, stream>>>(out + P_V1, out + P_V2, out + P_KK,
                                           out + O_IDX, out + P_VF, ws + WS_LOSS,
                                           (int*)(ws + WS_RC), (int*)(ws + WS_LIST));
    k_ref32<<<2048, 256, 0, stream>>>(x, embed, ws + WS_ENORM, out + O_IDX,
                                      (const int*)(ws + WS_RC), (const int*)(ws + WS_LIST),
                                      out + P_VF, ws + WS_LOSS,
                                      (int*)(ws + WS_RC2), (int*)(out + P_HLIST));
    k_ref64<<<2048, 256, 0, stream>>>(x, embed, enorm64, out + O_IDX,
                                      (const int*)(ws + WS_RC2), (const int*)(out + P_HLIST),
                                      out + P_VF, ws + WS_LOSS);
    k_cnt<<<NTOK / 256, 256, 0, stream>>>(out + O_IDX, ws + WS_CNT);
    k_dw<<<256, 256, 0, stream>>>(x, out + O_IDX, out + P_DW);
    k_fin_cs<<<1, 1024, 0, stream>>>(csz, ws + WS_CNT, out + O_NCS, ws + WS_SMOOTH);
    k_fin_emb<<<1024, 256, 0, stream>>>(ema, out + P_DW, ws + WS_SMOOTH,
                                        out + O_NEWEMB, out + O_NEE);
    k_quant<<<NTOK / 256, 256, 0, stream>>>(embed, out + O_IDX, out + O_OUT);
    k_loss<<<1, 1, 0, stream>>>(ws + WS_LOSS, out + O_LOSS);
}

// Round 7
// 1109.222 us; speedup vs baseline: 1.1750x; 1.0376x over previous
//
#include <hip/hip_runtime.h>
#include <cfloat>
#include <cstdint>

typedef unsigned short u16;

// Problem constants
#define NTOK   131072      // B*H*W
#define DIM    256
#define NCODE  1024
#define HW     4096
#define PLANE  1048576     // DIM*HW
#define DECAYF 0.9f
#define EPSF   1e-5f

// d_out float offsets (outputs concatenated in return order)
#define O_OUT     0
#define O_LOSS    33554432
#define O_IDX     33554433
#define O_NEWEMB  33685505
#define O_NCS     33947649
#define O_NEE     33948673

// scratch regions INSIDE O_OUT (float offsets) — k_quant overwrites O_OUT last
#define P_XS      0          // Xs bf16 [131072][256]; AFTER k_dist: dw partials [64][DIM][NCODE]
#define P_V1      16777216   // [8][131072]
#define P_V2      17825792
#define P_KK      18874368
#define P_VF      19922944   // [131072] final approx v1
#define P_BT      22151168   // Bt_sw swizzled tiles, 1 MB
#define P_ENORM64 22413312   // [1024] doubles (2048 floats), byte-offset %8 == 0
#define P_HLIST   22415360   // [32768] ints: hard-token list (fp32 gap <= MARGIN)

// ws float offsets (tiny, safe for any ws_size)
#define WS_ENORM  0
#define WS_CNT    1024
#define WS_LOSS   2048
#define WS_RC     2049
#define WS_RC2    2050       // hard count
#define WS_LIST   2051       // [32768]
#define WS_SMOOTH 34819

#define REF_CAP 32768
#define DELTA   0.25f
#define MARGIN  0.03f        // fp32 top-2 gap below which we go exact fp64
#define RT      16           // refine tokens per block-batch (k_ref32 only)
#define DWC     64           // dw chunks (was 8)

typedef __attribute__((ext_vector_type(8))) short bf16x8;
typedef __attribute__((ext_vector_type(4))) float f32x4;

__device__ __forceinline__ u16 bf16_rne(float f) {
    unsigned int u = __float_as_uint(f);
    unsigned int r = u + 0x7FFF + ((u >> 16) & 1);
    return (u16)(r >> 16);
}
__device__ __forceinline__ float bf16_to_f(u16 s) {
    return __uint_as_float(((unsigned int)s) << 16);
}
__device__ __forceinline__ void gload_lds16(const void* g, void* l) {
    __builtin_amdgcn_global_load_lds(
        (const __attribute__((address_space(1))) unsigned int*)g,
        (__attribute__((address_space(3))) unsigned int*)l, 16, 0, 0);
}

// ---------------------------------------------------------------- ||e_k||^2
__global__ void k_enorm(const float* __restrict__ embed, float* __restrict__ enorm,
                        double* __restrict__ enorm64) {
    int k = blockIdx.x * 256 + threadIdx.x;
    double s = 0.0;
    for (int d = 0; d < DIM; ++d) {
        float e = embed[(size_t)d * NCODE + k];
        s += (double)e * (double)e;
    }
    enorm[k] = (float)s;
    enorm64[k] = s;
}

// ------------------- k_xs: x [b][d][hw] fp32 -> Xs [n][256] bf16 (transpose) + sum(x^2)
__global__ __launch_bounds__(256) void k_xs(const float* __restrict__ x,
                                            u16* __restrict__ Xs,
                                            float* __restrict__ loss_acc)
{
    __shared__ float tile[64 * 65];
    __shared__ float red[256];
    const int tid = threadIdx.x;
    const int blk = blockIdx.x;          // 8192 = 32 b x 4 dc x 64 hwc
    const int b = blk >> 8;
    const int dc = (blk >> 6) & 3;
    const int hwc = blk & 63;
    const int d0 = dc * 64, hw0 = hwc * 64;
    const int r = tid >> 2, s = tid & 3;
    float sq = 0.f;
#pragma unroll
    for (int j = 0; j < 4; ++j) {
        float4 v = *(const float4*)&x[(size_t)b * PLANE + (size_t)(d0 + r) * HW + hw0 + s * 16 + j * 4];
        int c = s * 16 + j * 4;
        tile[r * 65 + c + 0] = v.x; tile[r * 65 + c + 1] = v.y;
        tile[r * 65 + c + 2] = v.z; tile[r * 65 + c + 3] = v.w;
        sq = fmaf(v.x, v.x, sq); sq = fmaf(v.y, v.y, sq);
        sq = fmaf(v.z, v.z, sq); sq = fmaf(v.w, v.w, sq);
    }
    __syncthreads();
    const int tk = tid >> 2, dq = tid & 3;
    u16 us[16];
#pragma unroll
    for (int j = 0; j < 16; ++j)
        us[j] = bf16_rne(tile[(dq * 16 + j) * 65 + tk]);
    size_t ob = (size_t)(b * 4096 + hw0 + tk) * 256 + d0 + dq * 16;
    *(uint4*)&Xs[ob]     = *(uint4*)&us[0];
    *(uint4*)&Xs[ob + 8] = *(uint4*)&us[8];
    red[tid] = sq; __syncthreads();
    for (int st = 128; st > 0; st >>= 1) {
        if (tid < st) red[tid] += red[tid + st];
        __syncthreads();
    }
    if (tid == 0) atomicAdd(loss_acc, red[0]);
}

// ------------------- k_bt: embed -> swizzled bf16 tiles Bt_sw[cc*16+kc][512 granules]
// kc 0..7 = E_hi rows (d = kc*32..), kc 8..15 = E_lo. Granule g of row n stored at slot (g+n)&3.
__global__ __launch_bounds__(256) void k_bt(const float* __restrict__ embed, u16* __restrict__ Bt)
{
    const int tile = blockIdx.x;          // 128 tiles
    const int cc = tile >> 4, kc = tile & 15;
    const int seg = kc >> 3, dbase = (kc & 7) * 32;
    const int tid = threadIdx.x;
#pragma unroll
    for (int g2 = 0; g2 < 2; ++g2) {
        int p = g2 * 256 + tid;
        int n = p >> 2, s = p & 3, lg = (s - n) & 3;
        int code = cc * 128 + n;
        u16 us[8];
#pragma unroll
        for (int e = 0; e < 8; ++e) {
            int d = dbase + lg * 8 + e;
            float E = embed[(size_t)d * NCODE + code];
            u16 hi = bf16_rne(E);
            us[e] = seg ? bf16_rne(E - bf16_to_f(hi)) : hi;
        }
        *(uint4*)&Bt[(size_t)tile * 4096 + (size_t)p * 8] = *(uint4*)&us[0];
    }
}

// ------------------- k_dist v4: bf16 MFMA GEMM (K=512) + per-chunk top-2
// Changes vs round-2 proven body:
//  (a) 2-phase double-buffered staging (T3 minimum): per step vmcnt(0) -> barrier
//      -> STAGE(next, buf^1) -> compute(buf). The drain waits on loads issued a
//      full compute-phase earlier (hidden); one barrier/step instead of two.
//      Sync order = R4's proven wait-BEFORE-barrier pattern.
//  (b) stripe-major XCD swizzle: the 8 cc-blocks of one token stripe are
//      adjacent-in-time on the same XCD -> Xs stripe L2-hot, FETCH drops.
__global__ __launch_bounds__(256) void k_dist(
    const u16* __restrict__ Xs, const u16* __restrict__ Bt,
    const float* __restrict__ enorm,
    float* __restrict__ pv1, float* __restrict__ pv2, float* __restrict__ pkk)
{
    __shared__ __align__(16) u16 lds[24576];   // 2 x {A 8KB | B0 8KB | B1 8KB}
    const int tid = threadIdx.x;
    const int w = tid >> 6, l = tid & 63;
    // bijective swizzle: bx = xcd + 8*(cc + 8*shi); stripe = shi*8 + xcd
    const int xcd = blockIdx.x & 7;
    const int q = blockIdx.x >> 3;
    const int cc = q & 7;
    const int n0 = ((q >> 3) * 8 + xcd) * 128;
    const int mh = w & 1, nh = w >> 1;
    const int lane15 = l & 15, quad = l >> 4;

    const u16* src[6];
    int dstoff[6];
#pragma unroll
    for (int r = 0; r < 6; ++r) {
        int p = r * 256 + w * 64 + l;
        dstoff[r] = (r * 256 + w * 64) * 8;
        if (p < 512) {
            int m = p >> 2, s = p & 3, lg = (s - m) & 3;
            src[r] = Xs + (size_t)(n0 + m) * 256 + lg * 8;
        } else {
            int qq2 = p - 512;
            int kcb = (qq2 >> 9) * 8;
            int qq = qq2 & 511;
            src[r] = Bt + (size_t)(cc * 16 + kcb) * 4096 + (size_t)qq * 8;
        }
    }

#define STAGE_K(kc8_, buf_) do {                                              \
    _Pragma("unroll")                                                         \
    for (int r_ = 0; r_ < 6; ++r_) {                                          \
        const u16* s_ = src[r_] + (r_ < 2 ? (size_t)(kc8_) * 32               \
                                          : (size_t)(kc8_) * 4096);           \
        gload_lds16(s_, &lds[(buf_) * 12288 + dstoff[r_]]);                   \
    } } while (0)

    f32x4 acc[4][4];
#pragma unroll
    for (int i = 0; i < 4; ++i)
#pragma unroll
        for (int j = 0; j < 4; ++j) acc[i][j] = (f32x4)0.f;

    STAGE_K(0, 0);                       // prologue

#pragma unroll 1
    for (int kc8 = 0; kc8 < 8; ++kc8) {
        // outstanding = exactly this step's 6 loads (issued one compute-phase ago)
        asm volatile("s_waitcnt vmcnt(0)" ::: "memory");
        __builtin_amdgcn_s_barrier();
        asm volatile("" ::: "memory");

        if (kc8 < 7) STAGE_K(kc8 + 1, (kc8 + 1) & 1);   // overlaps this compute

        const u16* buf = &lds[(kc8 & 1) * 12288];
        bf16x8 af[4];
#pragma unroll
        for (int mt = 0; mt < 4; ++mt) {
            int m = mh * 64 + mt * 16 + lane15;
            int slot = (quad + m) & 3;
            af[mt] = *(const bf16x8*)&buf[(size_t)(m * 4 + slot) * 8];
        }
#pragma unroll
        for (int seg = 0; seg < 2; ++seg) {
#pragma unroll
            for (int nt = 0; nt < 4; ++nt) {
                int n = nh * 64 + nt * 16 + lane15;
                int slot = (quad + n) & 3;
                bf16x8 bfr = *(const bf16x8*)&buf[(size_t)(512 + seg * 512 + n * 4 + slot) * 8];
#pragma unroll
                for (int mt = 0; mt < 4; ++mt)
                    acc[mt][nt] = __builtin_amdgcn_mfma_f32_16x16x32_bf16(af[mt], bfr, acc[mt][nt], 0, 0, 0);
            }
        }
    }
#undef STAGE_K

    float ev[4]; int ec[4];
#pragma unroll
    for (int nt = 0; nt < 4; ++nt) {
        ec[nt] = cc * 128 + nh * 64 + nt * 16 + lane15;
        ev[nt] = enorm[ec[nt]];
    }
    float r1[4][4], r2[4][4]; int rk[4][4];
#pragma unroll
    for (int mt = 0; mt < 4; ++mt)
#pragma unroll
        for (int rg = 0; rg < 4; ++rg) {
            float v1 = FLT_MAX, v2 = FLT_MAX; int k1 = 1 << 30;
#pragma unroll
            for (int nt = 0; nt < 4; ++nt) {
                float d = fmaf(-2.f, acc[mt][nt][rg], ev[nt]);
                if (d < v1) { v2 = v1; v1 = d; k1 = ec[nt]; }
                else v2 = fminf(v2, d);
            }
            r1[mt][rg] = v1; r2[mt][rg] = v2; rk[mt][rg] = k1;
        }
#pragma unroll
    for (int mask = 1; mask <= 8; mask <<= 1) {
#pragma unroll
        for (int mt = 0; mt < 4; ++mt)
#pragma unroll
            for (int rg = 0; rg < 4; ++rg) {
                float ov1 = __shfl_xor(r1[mt][rg], mask);
                float ov2 = __shfl_xor(r2[mt][rg], mask);
                int   ok  = __shfl_xor(rk[mt][rg], mask);
                if (ov1 < r1[mt][rg] || (ov1 == r1[mt][rg] && ok < rk[mt][rg])) {
                    r2[mt][rg] = fminf(r1[mt][rg], ov2);
                    r1[mt][rg] = ov1; rk[mt][rg] = ok;
                } else {
                    r2[mt][rg] = fminf(r2[mt][rg], ov1);
                }
            }
    }
    __syncthreads();
    float* epi = (float*)lds;   // [2 n-halves][128 tokens][3]
    if (lane15 == 0) {
#pragma unroll
        for (int mt = 0; mt < 4; ++mt)
#pragma unroll
            for (int rg = 0; rg < 4; ++rg) {
                int t = mh * 64 + mt * 16 + quad * 4 + rg;
                float* p = &epi[(nh * 128 + t) * 3];
                p[0] = r1[mt][rg]; p[1] = r2[mt][rg]; p[2] = __int_as_float(rk[mt][rg]);
            }
    }
    __syncthreads();
    if (tid < 128) {
        const float* p0 = &epi[tid * 3];
        const float* p1 = &epi[(128 + tid) * 3];
        float v1 = p0[0], v2 = p0[1]; int k1 = __float_as_int(p0[2]);
        float a1 = p1[0], a2 = p1[1]; int ak = __float_as_int(p1[2]);
        if (a1 < v1 || (a1 == v1 && ak < k1)) { v2 = fminf(v1, a2); v1 = a1; k1 = ak; }
        else v2 = fminf(v2, a1);
        size_t o = (size_t)cc * NTOK + n0 + tid;
        pv1[o] = v1; pv2[o] = v2; pkk[o] = (float)k1;
    }
}

// ------------------- k_amin: combine 8 chunk partials -> idx, vf, refine flags, sum(v1)
__global__ __launch_bounds__(256) void k_amin(
    const float* __restrict__ pv1, const float* __restrict__ pv2, const float* __restrict__ pkk,
    float* __restrict__ out_idx, float* __restrict__ vf, float* __restrict__ loss_acc,
    int* __restrict__ refcnt, int* __restrict__ reflist)
{
    const int n = blockIdx.x * 256 + threadIdx.x;
    float v1 = FLT_MAX, v2 = FLT_MAX; int k1 = 1 << 30;
    for (int cc = 0; cc < 8; ++cc) {
        float a1 = pv1[(size_t)cc * NTOK + n], a2 = pv2[(size_t)cc * NTOK + n];
        int ak = (int)pkk[(size_t)cc * NTOK + n];
        if (a1 < v1 || (a1 == v1 && ak < k1)) { v2 = fminf(v1, a2); v1 = a1; k1 = ak; }
        else v2 = fminf(v2, a1);
    }
    out_idx[n] = (float)k1;
    vf[n] = v1;
    if (v2 - v1 < DELTA) {
        int pos = atomicAdd(refcnt, 1);
        if (pos < REF_CAP) reflist[pos] = n;
    }
    __shared__ float red[256];
    red[threadIdx.x] = v1; __syncthreads();
    for (int s = 128; s > 0; s >>= 1) {
        if (threadIdx.x < s) red[threadIdx.x] += red[threadIdx.x + s];
        __syncthreads();
    }
    if (threadIdx.x == 0) atomicAdd(loss_acc, red[0]);
}

// ------------------- k_ref32: fp32 prefilter over flagged tokens (RT-batched; grid saturated)
__global__ __launch_bounds__(256) void k_ref32(
    const float* __restrict__ x, const float* __restrict__ embed,
    const float* __restrict__ enorm,
    float* __restrict__ out_idx, const int* __restrict__ refcnt,
    const int* __restrict__ reflist, const float* __restrict__ vf,
    float* __restrict__ loss_acc, int* __restrict__ hardcnt, int* __restrict__ hardlist)
{
    __shared__ float xm2t[DIM][RT + 1];
    __shared__ int toks[RT];
    __shared__ float wv1[4][RT], wv2[4][RT];
    __shared__ int wk1[4][RT];
    const int tid = threadIdx.x;
    const int w = tid >> 6;
    const int cnt = min(*refcnt, REF_CAP);
    for (int base = blockIdx.x * RT; base < cnt; base += gridDim.x * RT) {
        const int nb = min(RT, cnt - base);
        for (int j = 0; j < nb; ++j) {
            int n = reflist[base + j];
            if (tid == 0) toks[j] = n;
            int b = n >> 12, hw = n & 4095;
            xm2t[tid][j] = -2.f * x[(size_t)b * PLANE + (size_t)tid * HW + hw];
        }
        if (nb < RT)
            for (int j = nb; j < RT; ++j) xm2t[tid][j] = 0.f;
        __syncthreads();

        float b1[RT], b2[RT]; int k1[RT];
#pragma unroll
        for (int j = 0; j < RT; ++j) { b1[j] = FLT_MAX; b2[j] = FLT_MAX; k1[j] = 1 << 30; }
#pragma unroll 1
        for (int c = 0; c < 4; ++c) {
            const int k = c * 256 + tid;
            float acc[RT];
#pragma unroll
            for (int j = 0; j < RT; ++j) acc[j] = 0.f;
#pragma unroll 1
            for (int d0 = 0; d0 < DIM; d0 += 8) {
                float er[8];
#pragma unroll
                for (int dd = 0; dd < 8; ++dd)
                    er[dd] = embed[(size_t)(d0 + dd) * NCODE + k];
#pragma unroll
                for (int dd = 0; dd < 8; ++dd)
#pragma unroll
                    for (int j = 0; j < RT; ++j)
                        acc[j] = fmaf(er[dd], xm2t[d0 + dd][j], acc[j]);
            }
            float e2 = enorm[k];
#pragma unroll
            for (int j = 0; j < RT; ++j) {
                float dist = e2 + acc[j];
                if (dist < b1[j]) { b2[j] = b1[j]; b1[j] = dist; k1[j] = k; }
                else b2[j] = fminf(b2[j], dist);
            }
        }

#pragma unroll
        for (int m = 1; m < 64; m <<= 1) {
#pragma unroll
            for (int j = 0; j < RT; ++j) {
                float ov1 = __shfl_xor(b1[j], m);
                float ov2 = __shfl_xor(b2[j], m);
                int   ok  = __shfl_xor(k1[j], m);
                if (ov1 < b1[j] || (ov1 == b1[j] && ok < k1[j])) {
                    b2[j] = fminf(b1[j], ov2); b1[j] = ov1; k1[j] = ok;
                } else {
                    b2[j] = fminf(b2[j], ov1);
                }
            }
        }
        if ((tid & 63) == 0) {
#pragma unroll
            for (int j = 0; j < RT; ++j) { wv1[w][j] = b1[j]; wk1[w][j] = k1[j]; wv2[w][j] = b2[j]; }
        }
        __syncthreads();
        if (tid < nb) {
            float v1 = wv1[0][tid], v2 = wv2[0][tid]; int kk = wk1[0][tid];
#pragma unroll
            for (int wi = 1; wi < 4; ++wi) {
                float a1 = wv1[wi][tid], a2 = wv2[wi][tid]; int ak = wk1[wi][tid];
                if (a1 < v1 || (a1 == v1 && ak < kk)) { v2 = fminf(v1, a2); v1 = a1; kk = ak; }
                else v2 = fminf(v2, a1);
            }
            int n = toks[tid];
            if (v2 - v1 > MARGIN) {
                out_idx[n] = (float)kk;
                atomicAdd(loss_acc, v1 - vf[n]);
            } else {
                int pos = atomicAdd(hardcnt, 1);
                hardlist[pos] = n;
            }
        }
        __syncthreads();
    }
}

// ------------------- k_ref64 v3: exact fp64 argmin, one block per hard token
__global__ __launch_bounds__(256) void k_ref64(
    const float* __restrict__ x, const float* __restrict__ embed,
    const double* __restrict__ enorm64,
    float* __restrict__ out_idx, const int* __restrict__ hcnt,
    const int* __restrict__ hlist, const float* __restrict__ vf,
    float* __restrict__ loss_acc)
{
    __shared__ float xs[DIM];
    __shared__ double wv[4];
    __shared__ int wk[4];
    const int tid = threadIdx.x;
    const int w = tid >> 6, l = tid & 63;
    const int cnt = min(*hcnt, REF_CAP);
    for (int it = blockIdx.x; it < cnt; it += gridDim.x) {
        const int n = hlist[it];
        const int b = n >> 12, hw = n & 4095;
        xs[tid] = x[(size_t)b * PLANE + (size_t)tid * HW + hw];
        __syncthreads();
        double bv = 1e300; int bk = 1 << 30;
#pragma unroll 1
        for (int c = 0; c < 4; ++c) {
            const int k = c * 256 + tid;
            const float* ep = embed + k;
            double acc = 0.0;
#pragma unroll 8
            for (int d = 0; d < DIM; ++d)
                acc = fma((double)ep[(size_t)d * NCODE], (double)xs[d], acc);
            double dist = enorm64[k] - 2.0 * acc;
            if (dist < bv) { bv = dist; bk = k; }
        }
#pragma unroll
        for (int m = 1; m < 64; m <<= 1) {
            double ov = __shfl_xor(bv, m);
            int ok = __shfl_xor(bk, m);
            if (ov < bv || (ov == bv && ok < bk)) { bv = ov; bk = ok; }
        }
        if (l == 0) { wv[w] = bv; wk[w] = bk; }
        __syncthreads();
        if (tid == 0) {
            double v = wv[0]; int kk = wk[0];
#pragma unroll
            for (int wi = 1; wi < 4; ++wi) {
                if (wv[wi] < v || (wv[wi] == v && wk[wi] < kk)) { v = wv[wi]; kk = wk[wi]; }
            }
            out_idx[n] = (float)kk;
            atomicAdd(loss_acc, (float)(v - (double)vf[n]));
        }
        __syncthreads();
    }
}

// ------------------- k_cnt v2: LDS histogram -> <=1024 global atomics per block
__global__ __launch_bounds__(256) void k_cnt(const float* __restrict__ out_idx, float* __restrict__ cnt) {
    __shared__ float h[NCODE];
    const int tid = threadIdx.x;
    for (int i = tid; i < NCODE; i += 256) h[i] = 0.f;
    __syncthreads();
    const int base = blockIdx.x * 2048;        // grid 64 x 2048 tokens
#pragma unroll
    for (int t = 0; t < 8; ++t)
        unsafeAtomicAdd(&h[(int)out_idx[base + t * 256 + tid]], 1.0f);
    __syncthreads();
    for (int i = tid; i < NCODE; i += 256) {
        float v = h[i];
        if (v != 0.f) atomicAdd(&cnt[i], v);
    }
}

// ------------------- k_dw v2: 64 chunks (grid 2048 = 32 slices x 64 chunks)
// partials live in the P_XS region (free after k_dist), [DWC][DIM][NCODE].
__global__ __launch_bounds__(256) void k_dw(
    const float* __restrict__ x, const float* __restrict__ out_idx, float* __restrict__ part)
{
    __shared__ float tile[NCODE * 9];
    const int tid = threadIdx.x;
    const int slice = blockIdx.x & 31;
    const int chunk = blockIdx.x >> 5;
    const int d0 = slice * 8;
    for (int i = tid; i < NCODE * 9; i += 256) tile[i] = 0.f;
    __syncthreads();
    const int nbeg = chunk * (NTOK / DWC);
    for (int t = tid; t < NTOK / DWC; t += 256) {
        const int n = nbeg + t;
        const int b = n >> 12, hw = n & 4095;
        const int k = (int)out_idx[n];
        const float* xb = x + (size_t)b * PLANE + hw;
        float* tp = tile + k * 9;
#pragma unroll
        for (int dl = 0; dl < 8; ++dl)
            unsafeAtomicAdd(&tp[dl], xb[(size_t)(d0 + dl) * HW]);
    }
    __syncthreads();
    for (int i = tid; i < 8 * NCODE; i += 256) {
        const int dl = i >> 10, k = i & (NCODE - 1);
        part[((size_t)chunk * DIM + d0 + dl) * NCODE + k] = tile[k * 9 + dl];
    }
}

// ------------------- k_fin_cs: new_cluster_size + smoothing
__global__ __launch_bounds__(1024) void k_fin_cs(
    const float* __restrict__ cs_in, const float* __restrict__ cnt,
    float* __restrict__ out_ncs, float* __restrict__ smooth)
{
    const int k = threadIdx.x;
    float ncs = cs_in[k] * DECAYF + (1.f - DECAYF) * cnt[k];
    out_ncs[k] = ncs;
    __shared__ float red[1024];
    red[k] = ncs; __syncthreads();
    for (int s = 512; s > 0; s >>= 1) {
        if (k < s) red[k] += red[k + s];
        __syncthreads();
    }
    float n = red[0];
    smooth[k] = n * ((ncs + EPSF) / (n + ncs * EPSF));
}

// ------------------- k_fin_emb: sum DWC dw partials, new_ema_embed, new_embed
__global__ __launch_bounds__(256) void k_fin_emb(
    const float* __restrict__ ema, const float* __restrict__ part,
    const float* __restrict__ smooth, float* __restrict__ out_ne, float* __restrict__ out_nee)
{
    const int i = blockIdx.x * 256 + threadIdx.x;
    const int k = i & (NCODE - 1);
    float dw = 0.f;
    for (int c = 0; c < DWC; ++c) dw += part[(size_t)c * (DIM * NCODE) + i];
    float nee = ema[i] * DECAYF + (1.f - DECAYF) * dw;
    out_nee[i] = nee;
    out_ne[i] = nee / smooth[k];
}

// ------------------- k_quant v2: gather write, d split x4 for 4x more waves
__global__ __launch_bounds__(256) void k_quant(
    const float* __restrict__ embed, const float* __restrict__ out_idx, float* __restrict__ out_q)
{
    const int n = (blockIdx.x >> 2) * 256 + threadIdx.x;
    const int dc = blockIdx.x & 3;
    const int b = n >> 12, hw = n & 4095;
    const int idx = (int)out_idx[n];
    const size_t base = (size_t)b * PLANE + hw;
    const int dend = dc * 64 + 64;
    for (int d = dc * 64; d < dend; ++d)
        out_q[base + (size_t)d * HW] = embed[(size_t)d * NCODE + idx];
}

// ------------------- k_loss: finalize scalar
__global__ void k_loss(const float* __restrict__ loss_acc, float* __restrict__ out_loss) {
    out_loss[0] = 0.25f * loss_acc[0] / 33554432.f;
}

extern "C" void kernel_launch(void* const* d_in, const int* in_sizes, int n_in,
                              void* d_out, int out_size, void* d_ws, size_t ws_size,
                              hipStream_t stream) {
    const float* x     = (const float*)d_in[0];
    const float* embed = (const float*)d_in[1];
    const float* csz   = (const float*)d_in[2];
    const float* ema   = (const float*)d_in[3];
    float* out = (float*)d_out;
    float* ws  = (float*)d_ws;

    u16* Xs = (u16*)(out + P_XS);
    u16* Bt = (u16*)(out + P_BT);
    double* enorm64 = (double*)(out + P_ENORM64);

    // zero cnt[1024], loss, refcnt, hardcnt
    hipMemsetAsync(ws + WS_CNT, 0, (size_t)(WS_RC2 + 1 - WS_CNT) * sizeof(float), stream);

    k_enorm<<<4, 256, 0, stream>>>(embed, ws + WS_ENORM, enorm64);
    k_xs<<<8192, 256, 0, stream>>>(x, Xs, ws + WS_LOSS);
    k_bt<<<128, 256, 0, stream>>>(embed, Bt);
    k_dist<<<8192, 256, 0, stream>>>(Xs, Bt, ws + WS_ENORM,
                                     out + P_V1, out + P_V2, out + P_KK);
    k_amin<<<NTOK / 256, 256, 0, stream>>>(out + P_V1, out + P_V2, out + P_KK,
                                           out + O_IDX, out + P_VF, ws + WS_LOSS,
                                           (int*)(ws + WS_RC), (int*)(ws + WS_LIST));
    k_ref32<<<2048, 256, 0, stream>>>(x, embed, ws + WS_ENORM, out + O_IDX,
                                      (const int*)(ws + WS_RC), (const int*)(ws + WS_LIST),
                                      out + P_VF, ws + WS_LOSS,
                                      (int*)(ws + WS_RC2), (int*)(out + P_HLIST));
    k_ref64<<<2048, 256, 0, stream>>>(x, embed, enorm64, out + O_IDX,
                                      (const int*)(ws + WS_RC2), (const int*)(out + P_HLIST),
                                      out + P_VF, ws + WS_LOSS);
    k_cnt<<<64, 256, 0, stream>>>(out + O_IDX, ws + WS_CNT);
    // dw partials reuse the Xs region (k_dist is done with it); k_quant overwrites later
    k_dw<<<32 * DWC, 256, 0, stream>>>(x, out + O_IDX, out + P_XS);
    k_fin_cs<<<1, 1024, 0, stream>>>(csz, ws + WS_CNT, out + O_NCS, ws + WS_SMOOTH);
    k_fin_emb<<<1024, 256, 0, stream>>>(ema, out + P_XS, ws + WS_SMOOTH,
                                        out + O_NEWEMB, out + O_NEE);
    k_quant<<<NTOK / 256 * 4, 256, 0, stream>>>(embed, out + O_IDX, out + O_OUT);
    k_loss<<<1, 1, 0, stream>>>(ws + WS_LOSS, out + O_LOSS);
}

// Round 8
// 1040.013 us; speedup vs baseline: 1.2532x; 1.0665x over previous
//
#include <hip/hip_runtime.h>
#include <cfloat>
#include <cstdint>

typedef unsigned short u16;

// Problem constants
#define NTOK   131072      // B*H*W
#define DIM    256
#define NCODE  1024
#define HW     4096
#define PLANE  1048576     // DIM*HW
#define DECAYF 0.9f
#define EPSF   1e-5f

// d_out float offsets (outputs concatenated in return order)
#define O_OUT     0
#define O_LOSS    33554432
#define O_IDX     33554433
#define O_NEWEMB  33685505
#define O_NCS     33947649
#define O_NEE     33948673

// scratch regions INSIDE O_OUT (float offsets) — k_quant overwrites O_OUT last
#define P_XS      0          // Xs bf16 [131072][256]; AFTER k_dist: dw partials [64][DIM][NCODE]
#define P_V1      16777216   // [8][131072]
#define P_V2      17825792
#define P_KK      18874368
#define P_VF      19922944   // [131072] final approx v1
#define P_BT      22151168   // Bt_sw swizzled tiles, 1 MB
#define P_ENORM64 22413312   // [1024] doubles (2048 floats), byte-offset %8 == 0
#define P_HLIST   22415360   // [32768] ints: hard-token list (fp32 gap <= MARGIN)

// ws float offsets (tiny, safe for any ws_size)
#define WS_ENORM  0
#define WS_CNT    1024
#define WS_LOSS   2048
#define WS_RC     2049
#define WS_RC2    2050       // hard count
#define WS_LIST   2051       // [32768]
#define WS_SMOOTH 34819

#define REF_CAP 32768
#define DELTA   0.25f
#define MARGIN  0.03f        // fp32 top-2 gap below which we go exact fp64
#define RT      16           // refine tokens per block-batch (k_ref32 only)
#define DWC     64           // dw chunks

typedef __attribute__((ext_vector_type(8))) short bf16x8;
typedef __attribute__((ext_vector_type(4))) float f32x4;

__device__ __forceinline__ u16 bf16_rne(float f) {
    unsigned int u = __float_as_uint(f);
    unsigned int r = u + 0x7FFF + ((u >> 16) & 1);
    return (u16)(r >> 16);
}
__device__ __forceinline__ float bf16_to_f(u16 s) {
    return __uint_as_float(((unsigned int)s) << 16);
}
__device__ __forceinline__ void gload_lds16(const void* g, void* l) {
    __builtin_amdgcn_global_load_lds(
        (const __attribute__((address_space(1))) unsigned int*)g,
        (__attribute__((address_space(3))) unsigned int*)l, 16, 0, 0);
}

// ---------------------------------------------------------------- ||e_k||^2
__global__ void k_enorm(const float* __restrict__ embed, float* __restrict__ enorm,
                        double* __restrict__ enorm64) {
    int k = blockIdx.x * 256 + threadIdx.x;
    double s = 0.0;
    for (int d = 0; d < DIM; ++d) {
        float e = embed[(size_t)d * NCODE + k];
        s += (double)e * (double)e;
    }
    enorm[k] = (float)s;
    enorm64[k] = s;
}

// ------------------- k_xs: x [b][d][hw] fp32 -> Xs [n][256] bf16 (transpose) + sum(x^2)
__global__ __launch_bounds__(256) void k_xs(const float* __restrict__ x,
                                            u16* __restrict__ Xs,
                                            float* __restrict__ loss_acc)
{
    __shared__ float tile[64 * 65];
    __shared__ float red[256];
    const int tid = threadIdx.x;
    const int blk = blockIdx.x;          // 8192 = 32 b x 4 dc x 64 hwc
    const int b = blk >> 8;
    const int dc = (blk >> 6) & 3;
    const int hwc = blk & 63;
    const int d0 = dc * 64, hw0 = hwc * 64;
    const int r = tid >> 2, s = tid & 3;
    float sq = 0.f;
#pragma unroll
    for (int j = 0; j < 4; ++j) {
        float4 v = *(const float4*)&x[(size_t)b * PLANE + (size_t)(d0 + r) * HW + hw0 + s * 16 + j * 4];
        int c = s * 16 + j * 4;
        tile[r * 65 + c + 0] = v.x; tile[r * 65 + c + 1] = v.y;
        tile[r * 65 + c + 2] = v.z; tile[r * 65 + c + 3] = v.w;
        sq = fmaf(v.x, v.x, sq); sq = fmaf(v.y, v.y, sq);
        sq = fmaf(v.z, v.z, sq); sq = fmaf(v.w, v.w, sq);
    }
    __syncthreads();
    const int tk = tid >> 2, dq = tid & 3;
    u16 us[16];
#pragma unroll
    for (int j = 0; j < 16; ++j)
        us[j] = bf16_rne(tile[(dq * 16 + j) * 65 + tk]);
    size_t ob = (size_t)(b * 4096 + hw0 + tk) * 256 + d0 + dq * 16;
    *(uint4*)&Xs[ob]     = *(uint4*)&us[0];
    *(uint4*)&Xs[ob + 8] = *(uint4*)&us[8];
    red[tid] = sq; __syncthreads();
    for (int st = 128; st > 0; st >>= 1) {
        if (tid < st) red[tid] += red[tid + st];
        __syncthreads();
    }
    if (tid == 0) atomicAdd(loss_acc, red[0]);
}

// ------------------- k_bt: embed -> swizzled bf16 tiles Bt_sw[cc*16+kc][512 granules]
// kc 0..7 = E_hi rows (d = kc*32..), kc 8..15 = E_lo.
// Granule g of row n stored at slot (g + n + (n>>2)) & 3  (<=2-way bank aliasing on read;
// 2-way is free per m136). Swizzle correctness-proven in R4.
__global__ __launch_bounds__(256) void k_bt(const float* __restrict__ embed, u16* __restrict__ Bt)
{
    const int tile = blockIdx.x;          // 128 tiles
    const int cc = tile >> 4, kc = tile & 15;
    const int seg = kc >> 3, dbase = (kc & 7) * 32;
    const int tid = threadIdx.x;
#pragma unroll
    for (int g2 = 0; g2 < 2; ++g2) {
        int p = g2 * 256 + tid;
        int n = p >> 2, s = p & 3, lg = (s - n - (n >> 2)) & 3;
        int code = cc * 128 + n;
        u16 us[8];
#pragma unroll
        for (int e = 0; e < 8; ++e) {
            int d = dbase + lg * 8 + e;
            float E = embed[(size_t)d * NCODE + code];
            u16 hi = bf16_rne(E);
            us[e] = seg ? bf16_rne(E - bf16_to_f(hi)) : hi;
        }
        *(uint4*)&Bt[(size_t)tile * 4096 + (size_t)p * 8] = *(uint4*)&us[0];
    }
}

// ------------------- k_dist v5: 256 tok x 128 codes per block, mt=8
// - LDS bytes/MFMA 384 -> 256 (16 reads per 64 MFMA/wave/step); half the blocks
//   -> half the prologue/epilogue overhead (8-step K-loop is short).
// - 2-way-max bank swizzle slot=(quad+m+(m>>2))&3 on A and B reads (R4-proven).
// - Structure = R2/R6 proven 2-barrier single-buffer; XCD swizzle kept.
// - Epilogue streams per-mt (12 live regs, static indexing) to fit 256-VGPR cap.
__global__ __launch_bounds__(256, 2) void k_dist(
    const u16* __restrict__ Xs, const u16* __restrict__ Bt,
    const float* __restrict__ enorm,
    float* __restrict__ pv1, float* __restrict__ pv2, float* __restrict__ pkk)
{
    __shared__ __align__(16) u16 lds[16384];   // A 16KB | B 16KB (epilogue reuses as float[])
    const int tid = threadIdx.x;
    const int w = tid >> 6, l = tid & 63;
    // grid 4096 = 8 xcd x 8 cc x 64 shi ; stripe = shi*8+xcd (512 stripes, bijective)
    const int xcd = blockIdx.x & 7;
    const int q = blockIdx.x >> 3;
    const int cc = q & 7;
    const int n0 = ((q >> 3) * 8 + xcd) * 256;
    const int mh = w & 1, nh = w >> 1;
    const int lane15 = l & 15, quad = l >> 4;

    // staging: 8 rounds x 256 thr x 16B = 32KB/step. rounds 0-3: A, 4-5: B seg0, 6-7: B seg1
    const u16* src[8];
    u16* dstp[8];
#pragma unroll
    for (int r = 0; r < 8; ++r) {
        int p = r * 256 + tid;
        int pbase = r * 256 + w * 64;
        if (r < 4) {
            int m = p >> 2, s = p & 3, lg = (s - m - (m >> 2)) & 3;
            src[r] = Xs + (size_t)(n0 + m) * 256 + lg * 8;
            dstp[r] = &lds[(size_t)pbase * 8];
        } else {
            int q2 = p - 1024;
            int segi = q2 >> 9, pos = q2 & 511;
            src[r] = Bt + (size_t)(cc * 16 + segi * 8) * 4096 + (size_t)pos * 8;
            dstp[r] = &lds[8192 + (size_t)(pbase - 1024) * 8];
        }
    }

    f32x4 acc[8][4];
#pragma unroll
    for (int i = 0; i < 8; ++i)
#pragma unroll
        for (int j = 0; j < 4; ++j) acc[i][j] = (f32x4)0.f;

    for (int kc8 = 0; kc8 < 8; ++kc8) {
        __syncthreads();
#pragma unroll
        for (int r = 0; r < 8; ++r) {
            const u16* s = src[r] + (r < 4 ? (size_t)kc8 * 32 : (size_t)kc8 * 4096);
            gload_lds16(s, dstp[r]);
        }
        __syncthreads();

        bf16x8 af[8];
#pragma unroll
        for (int mt = 0; mt < 8; ++mt) {
            int m = mh * 128 + mt * 16 + lane15;
            int slot = (quad + m + (m >> 2)) & 3;
            af[mt] = *(const bf16x8*)&lds[(size_t)(m * 4 + slot) * 8];
        }
#pragma unroll
        for (int seg = 0; seg < 2; ++seg) {
#pragma unroll
            for (int nt = 0; nt < 4; ++nt) {
                int n = nh * 64 + nt * 16 + lane15;
                int slot = (quad + n + (n >> 2)) & 3;
                bf16x8 bfr = *(const bf16x8*)&lds[8192 + seg * 4096 + (size_t)(n * 4 + slot) * 8];
#pragma unroll
                for (int mt = 0; mt < 8; ++mt)
                    acc[mt][nt] = __builtin_amdgcn_mfma_f32_16x16x32_bf16(af[mt], bfr, acc[mt][nt], 0, 0, 0);
            }
        }
    }

    // ---- epilogue: dist = ||e||^2 - 2 dot ; per-token top-2 over this cc's 128 codes
    float ev[4]; int ec[4];
#pragma unroll
    for (int nt = 0; nt < 4; ++nt) {
        ec[nt] = cc * 128 + nh * 64 + nt * 16 + lane15;
        ev[nt] = enorm[ec[nt]];
    }
    __syncthreads();                       // all fragment reads done before epi overwrite
    float* epi = (float*)lds;              // [2 n-halves][256 tokens][3]
#pragma unroll
    for (int mt = 0; mt < 8; ++mt) {
        float r1[4], r2[4]; int rk[4];
#pragma unroll
        for (int rg = 0; rg < 4; ++rg) {
            float v1 = FLT_MAX, v2 = FLT_MAX; int k1 = 1 << 30;
#pragma unroll
            for (int nt = 0; nt < 4; ++nt) {
                float d = fmaf(-2.f, acc[mt][nt][rg], ev[nt]);
                if (d < v1) { v2 = v1; v1 = d; k1 = ec[nt]; }
                else v2 = fminf(v2, d);
            }
            r1[rg] = v1; r2[rg] = v2; rk[rg] = k1;
        }
#pragma unroll
        for (int mask = 1; mask <= 8; mask <<= 1) {
#pragma unroll
            for (int rg = 0; rg < 4; ++rg) {
                float ov1 = __shfl_xor(r1[rg], mask);
                float ov2 = __shfl_xor(r2[rg], mask);
                int   ok  = __shfl_xor(rk[rg], mask);
                if (ov1 < r1[rg] || (ov1 == r1[rg] && ok < rk[rg])) {
                    r2[rg] = fminf(r1[rg], ov2);
                    r1[rg] = ov1; rk[rg] = ok;
                } else {
                    r2[rg] = fminf(r2[rg], ov1);
                }
            }
        }
        if (lane15 == 0) {
#pragma unroll
            for (int rg = 0; rg < 4; ++rg) {
                int t = mh * 128 + mt * 16 + quad * 4 + rg;
                float* pp = &epi[(nh * 256 + t) * 3];
                pp[0] = r1[rg]; pp[1] = r2[rg]; pp[2] = __int_as_float(rk[rg]);
            }
        }
    }
    __syncthreads();
    {
        const float* p0 = &epi[tid * 3];
        const float* p1 = &epi[(256 + tid) * 3];
        float v1 = p0[0], v2 = p0[1]; int k1 = __float_as_int(p0[2]);
        float a1 = p1[0], a2 = p1[1]; int ak = __float_as_int(p1[2]);
        if (a1 < v1 || (a1 == v1 && ak < k1)) { v2 = fminf(v1, a2); v1 = a1; k1 = ak; }
        else v2 = fminf(v2, a1);
        size_t o = (size_t)cc * NTOK + n0 + tid;
        pv1[o] = v1; pv2[o] = v2; pkk[o] = (float)k1;
    }
}

// ------------------- k_amin: combine 8 chunk partials -> idx, vf, refine flags, sum(v1)
__global__ __launch_bounds__(256) void k_amin(
    const float* __restrict__ pv1, const float* __restrict__ pv2, const float* __restrict__ pkk,
    float* __restrict__ out_idx, float* __restrict__ vf, float* __restrict__ loss_acc,
    int* __restrict__ refcnt, int* __restrict__ reflist)
{
    const int n = blockIdx.x * 256 + threadIdx.x;
    float v1 = FLT_MAX, v2 = FLT_MAX; int k1 = 1 << 30;
    for (int cc = 0; cc < 8; ++cc) {
        float a1 = pv1[(size_t)cc * NTOK + n], a2 = pv2[(size_t)cc * NTOK + n];
        int ak = (int)pkk[(size_t)cc * NTOK + n];
        if (a1 < v1 || (a1 == v1 && ak < k1)) { v2 = fminf(v1, a2); v1 = a1; k1 = ak; }
        else v2 = fminf(v2, a1);
    }
    out_idx[n] = (float)k1;
    vf[n] = v1;
    if (v2 - v1 < DELTA) {
        int pos = atomicAdd(refcnt, 1);
        if (pos < REF_CAP) reflist[pos] = n;
    }
    __shared__ float red[256];
    red[threadIdx.x] = v1; __syncthreads();
    for (int s = 128; s > 0; s >>= 1) {
        if (threadIdx.x < s) red[threadIdx.x] += red[threadIdx.x + s];
        __syncthreads();
    }
    if (threadIdx.x == 0) atomicAdd(loss_acc, red[0]);
}

// ------------------- k_ref32: fp32 prefilter over flagged tokens (RT-batched; grid saturated)
__global__ __launch_bounds__(256) void k_ref32(
    const float* __restrict__ x, const float* __restrict__ embed,
    const float* __restrict__ enorm,
    float* __restrict__ out_idx, const int* __restrict__ refcnt,
    const int* __restrict__ reflist, const float* __restrict__ vf,
    float* __restrict__ loss_acc, int* __restrict__ hardcnt, int* __restrict__ hardlist)
{
    __shared__ float xm2t[DIM][RT + 1];
    __shared__ int toks[RT];
    __shared__ float wv1[4][RT], wv2[4][RT];
    __shared__ int wk1[4][RT];
    const int tid = threadIdx.x;
    const int w = tid >> 6;
    const int cnt = min(*refcnt, REF_CAP);
    for (int base = blockIdx.x * RT; base < cnt; base += gridDim.x * RT) {
        const int nb = min(RT, cnt - base);
        for (int j = 0; j < nb; ++j) {
            int n = reflist[base + j];
            if (tid == 0) toks[j] = n;
            int b = n >> 12, hw = n & 4095;
            xm2t[tid][j] = -2.f * x[(size_t)b * PLANE + (size_t)tid * HW + hw];
        }
        if (nb < RT)
            for (int j = nb; j < RT; ++j) xm2t[tid][j] = 0.f;
        __syncthreads();

        float b1[RT], b2[RT]; int k1[RT];
#pragma unroll
        for (int j = 0; j < RT; ++j) { b1[j] = FLT_MAX; b2[j] = FLT_MAX; k1[j] = 1 << 30; }
#pragma unroll 1
        for (int c = 0; c < 4; ++c) {
            const int k = c * 256 + tid;
            float acc[RT];
#pragma unroll
            for (int j = 0; j < RT; ++j) acc[j] = 0.f;
#pragma unroll 1
            for (int d0 = 0; d0 < DIM; d0 += 8) {
                float er[8];
#pragma unroll
                for (int dd = 0; dd < 8; ++dd)
                    er[dd] = embed[(size_t)(d0 + dd) * NCODE + k];
#pragma unroll
                for (int dd = 0; dd < 8; ++dd)
#pragma unroll
                    for (int j = 0; j < RT; ++j)
                        acc[j] = fmaf(er[dd], xm2t[d0 + dd][j], acc[j]);
            }
            float e2 = enorm[k];
#pragma unroll
            for (int j = 0; j < RT; ++j) {
                float dist = e2 + acc[j];
                if (dist < b1[j]) { b2[j] = b1[j]; b1[j] = dist; k1[j] = k; }
                else b2[j] = fminf(b2[j], dist);
            }
        }

#pragma unroll
        for (int m = 1; m < 64; m <<= 1) {
#pragma unroll
            for (int j = 0; j < RT; ++j) {
                float ov1 = __shfl_xor(b1[j], m);
                float ov2 = __shfl_xor(b2[j], m);
                int   ok  = __shfl_xor(k1[j], m);
                if (ov1 < b1[j] || (ov1 == b1[j] && ok < k1[j])) {
                    b2[j] = fminf(b1[j], ov2); b1[j] = ov1; k1[j] = ok;
                } else {
                    b2[j] = fminf(b2[j], ov1);
                }
            }
        }
        if ((tid & 63) == 0) {
#pragma unroll
            for (int j = 0; j < RT; ++j) { wv1[w][j] = b1[j]; wk1[w][j] = k1[j]; wv2[w][j] = b2[j]; }
        }
        __syncthreads();
        if (tid < nb) {
            float v1 = wv1[0][tid], v2 = wv2[0][tid]; int kk = wk1[0][tid];
#pragma unroll
            for (int wi = 1; wi < 4; ++wi) {
                float a1 = wv1[wi][tid], a2 = wv2[wi][tid]; int ak = wk1[wi][tid];
                if (a1 < v1 || (a1 == v1 && ak < kk)) { v2 = fminf(v1, a2); v1 = a1; kk = ak; }
                else v2 = fminf(v2, a1);
            }
            int n = toks[tid];
            if (v2 - v1 > MARGIN) {
                out_idx[n] = (float)kk;
                atomicAdd(loss_acc, v1 - vf[n]);
            } else {
                int pos = atomicAdd(hardcnt, 1);
                hardlist[pos] = n;
            }
        }
        __syncthreads();
    }
}

// ------------------- k_ref64 v3: exact fp64 argmin, one block per hard token
__global__ __launch_bounds__(256) void k_ref64(
    const float* __restrict__ x, const float* __restrict__ embed,
    const double* __restrict__ enorm64,
    float* __restrict__ out_idx, const int* __restrict__ hcnt,
    const int* __restrict__ hlist, const float* __restrict__ vf,
    float* __restrict__ loss_acc)
{
    __shared__ float xs[DIM];
    __shared__ double wv[4];
    __shared__ int wk[4];
    const int tid = threadIdx.x;
    const int w = tid >> 6, l = tid & 63;
    const int cnt = min(*hcnt, REF_CAP);
    for (int it = blockIdx.x; it < cnt; it += gridDim.x) {
        const int n = hlist[it];
        const int b = n >> 12, hw = n & 4095;
        xs[tid] = x[(size_t)b * PLANE + (size_t)tid * HW + hw];
        __syncthreads();
        double bv = 1e300; int bk = 1 << 30;
#pragma unroll 1
        for (int c = 0; c < 4; ++c) {
            const int k = c * 256 + tid;
            const float* ep = embed + k;
            double acc = 0.0;
#pragma unroll 8
            for (int d = 0; d < DIM; ++d)
                acc = fma((double)ep[(size_t)d * NCODE], (double)xs[d], acc);
            double dist = enorm64[k] - 2.0 * acc;
            if (dist < bv) { bv = dist; bk = k; }
        }
#pragma unroll
        for (int m = 1; m < 64; m <<= 1) {
            double ov = __shfl_xor(bv, m);
            int ok = __shfl_xor(bk, m);
            if (ov < bv || (ov == bv && ok < bk)) { bv = ov; bk = ok; }
        }
        if (l == 0) { wv[w] = bv; wk[w] = bk; }
        __syncthreads();
        if (tid == 0) {
            double v = wv[0]; int kk = wk[0];
#pragma unroll
            for (int wi = 1; wi < 4; ++wi) {
                if (wv[wi] < v || (wv[wi] == v && wk[wi] < kk)) { v = wv[wi]; kk = wk[wi]; }
            }
            out_idx[n] = (float)kk;
            atomicAdd(loss_acc, (float)(v - (double)vf[n]));
        }
        __syncthreads();
    }
}

// ------------------- k_cnt v2: LDS histogram -> <=1024 global atomics per block
__global__ __launch_bounds__(256) void k_cnt(const float* __restrict__ out_idx, float* __restrict__ cnt) {
    __shared__ float h[NCODE];
    const int tid = threadIdx.x;
    for (int i = tid; i < NCODE; i += 256) h[i] = 0.f;
    __syncthreads();
    const int base = blockIdx.x * 2048;        // grid 64 x 2048 tokens
#pragma unroll
    for (int t = 0; t < 8; ++t)
        unsafeAtomicAdd(&h[(int)out_idx[base + t * 256 + tid]], 1.0f);
    __syncthreads();
    for (int i = tid; i < NCODE; i += 256) {
        float v = h[i];
        if (v != 0.f) atomicAdd(&cnt[i], v);
    }
}

// ------------------- k_dw v2: 64 chunks (grid 2048 = 32 slices x 64 chunks)
__global__ __launch_bounds__(256) void k_dw(
    const float* __restrict__ x, const float* __restrict__ out_idx, float* __restrict__ part)
{
    __shared__ float tile[NCODE * 9];
    const int tid = threadIdx.x;
    const int slice = blockIdx.x & 31;
    const int chunk = blockIdx.x >> 5;
    const int d0 = slice * 8;
    for (int i = tid; i < NCODE * 9; i += 256) tile[i] = 0.f;
    __syncthreads();
    const int nbeg = chunk * (NTOK / DWC);
    for (int t = tid; t < NTOK / DWC; t += 256) {
        const int n = nbeg + t;
        const int b = n >> 12, hw = n & 4095;
        const int k = (int)out_idx[n];
        const float* xb = x + (size_t)b * PLANE + hw;
        float* tp = tile + k * 9;
#pragma unroll
        for (int dl = 0; dl < 8; ++dl)
            unsafeAtomicAdd(&tp[dl], xb[(size_t)(d0 + dl) * HW]);
    }
    __syncthreads();
    for (int i = tid; i < 8 * NCODE; i += 256) {
        const int dl = i >> 10, k = i & (NCODE - 1);
        part[((size_t)chunk * DIM + d0 + dl) * NCODE + k] = tile[k * 9 + dl];
    }
}

// ------------------- k_fin_cs: new_cluster_size + smoothing
__global__ __launch_bounds__(1024) void k_fin_cs(
    const float* __restrict__ cs_in, const float* __restrict__ cnt,
    float* __restrict__ out_ncs, float* __restrict__ smooth)
{
    const int k = threadIdx.x;
    float ncs = cs_in[k] * DECAYF + (1.f - DECAYF) * cnt[k];
    out_ncs[k] = ncs;
    __shared__ float red[1024];
    red[k] = ncs; __syncthreads();
    for (int s = 512; s > 0; s >>= 1) {
        if (k < s) red[k] += red[k + s];
        __syncthreads();
    }
    float n = red[0];
    smooth[k] = n * ((ncs + EPSF) / (n + ncs * EPSF));
}

// ------------------- k_fin_emb: sum DWC dw partials, new_ema_embed, new_embed
__global__ __launch_bounds__(256) void k_fin_emb(
    const float* __restrict__ ema, const float* __restrict__ part,
    const float* __restrict__ smooth, float* __restrict__ out_ne, float* __restrict__ out_nee)
{
    const int i = blockIdx.x * 256 + threadIdx.x;
    const int k = i & (NCODE - 1);
    float dw = 0.f;
    for (int c = 0; c < DWC; ++c) dw += part[(size_t)c * (DIM * NCODE) + i];
    float nee = ema[i] * DECAYF + (1.f - DECAYF) * dw;
    out_nee[i] = nee;
    out_ne[i] = nee / smooth[k];
}

// ------------------- k_quant v2: gather write, d split x4
__global__ __launch_bounds__(256) void k_quant(
    const float* __restrict__ embed, const float* __restrict__ out_idx, float* __restrict__ out_q)
{
    const int n = (blockIdx.x >> 2) * 256 + threadIdx.x;
    const int dc = blockIdx.x & 3;
    const int b = n >> 12, hw = n & 4095;
    const int idx = (int)out_idx[n];
    const size_t base = (size_t)b * PLANE + hw;
    const int dend = dc * 64 + 64;
    for (int d = dc * 64; d < dend; ++d)
        out_q[base + (size_t)d * HW] = embed[(size_t)d * NCODE + idx];
}

// ------------------- k_loss: finalize scalar
__global__ void k_loss(const float* __restrict__ loss_acc, float* __restrict__ out_loss) {
    out_loss[0] = 0.25f * loss_acc[0] / 33554432.f;
}

extern "C" void kernel_launch(void* const* d_in, const int* in_sizes, int n_in,
                              void* d_out, int out_size, void* d_ws, size_t ws_size,
                              hipStream_t stream) {
    const float* x     = (const float*)d_in[0];
    const float* embed = (const float*)d_in[1];
    const float* csz   = (const float*)d_in[2];
    const float* ema   = (const float*)d_in[3];
    float* out = (float*)d_out;
    float* ws  = (float*)d_ws;

    u16* Xs = (u16*)(out + P_XS);
    u16* Bt = (u16*)(out + P_BT);
    double* enorm64 = (double*)(out + P_ENORM64);

    // zero cnt[1024], loss, refcnt, hardcnt
    hipMemsetAsync(ws + WS_CNT, 0, (size_t)(WS_RC2 + 1 - WS_CNT) * sizeof(float), stream);

    k_enorm<<<4, 256, 0, stream>>>(embed, ws + WS_ENORM, enorm64);
    k_xs<<<8192, 256, 0, stream>>>(x, Xs, ws + WS_LOSS);
    k_bt<<<128, 256, 0, stream>>>(embed, Bt);
    k_dist<<<4096, 256, 0, stream>>>(Xs, Bt, ws + WS_ENORM,
                                     out + P_V1, out + P_V2, out + P_KK);
    k_amin<<<NTOK / 256, 256, 0, stream>>>(out + P_V1, out + P_V2, out + P_KK,
                                           out + O_IDX, out + P_VF, ws + WS_LOSS,
                                           (int*)(ws + WS_RC), (int*)(ws + WS_LIST));
    k_ref32<<<2048, 256, 0, stream>>>(x, embed, ws + WS_ENORM, out + O_IDX,
                                      (const int*)(ws + WS_RC), (const int*)(ws + WS_LIST),
                                      out + P_VF, ws + WS_LOSS,
                                      (int*)(ws + WS_RC2), (int*)(out + P_HLIST));
    k_ref64<<<2048, 256, 0, stream>>>(x, embed, enorm64, out + O_IDX,
                                      (const int*)(ws + WS_RC2), (const int*)(out + P_HLIST),
                                      out + P_VF, ws + WS_LOSS);
    k_cnt<<<64, 256, 0, stream>>>(out + O_IDX, ws + WS_CNT);
    k_dw<<<32 * DWC, 256, 0, stream>>>(x, out + O_IDX, out + P_XS);
    k_fin_cs<<<1, 1024, 0, stream>>>(csz, ws + WS_CNT, out + O_NCS, ws + WS_SMOOTH);
    k_fin_emb<<<1024, 256, 0, stream>>>(ema, out + P_XS, ws + WS_SMOOTH,
                                        out + O_NEWEMB, out + O_NEE);
    k_quant<<<NTOK / 256 * 4, 256, 0, stream>>>(embed, out + O_IDX, out + O_OUT);
    k_loss<<<1, 1, 0, stream>>>(ws + WS_LOSS, out + O_LOSS);
}